// Round 2
// baseline (761.882 us; speedup 1.0000x reference)
//
#include <hip/hip_runtime.h>
#include <hip/hip_bf16.h>
#include <cstdint>

#define N_NODES 8192
#define N_EDGES 131072
#define NTOT 139264          // N_NODES + N_EDGES
#define H 128

typedef __attribute__((ext_vector_type(8))) short short8;
typedef __attribute__((ext_vector_type(4))) float floatx4;

__device__ __forceinline__ ushort f2bf(float f) {
    union { float f; uint32_t u; } v; v.f = f;
    uint32_t r = v.u + 0x7fffu + ((v.u >> 16) & 1u);   // RNE
    return (ushort)(r >> 16);
}
__device__ __forceinline__ float bf2f(ushort u) {
    union { uint32_t u; float f; } v; v.u = ((uint32_t)u) << 16;
    return v.f;
}
__device__ __forceinline__ short8 lds_load8(const ushort* p) {
    union { short8 s; uint2 u[2]; } r;
    r.u[0] = *(const uint2*)p;
    r.u[1] = *(const uint2*)(p + 4);
    return r.s;
}
__device__ __forceinline__ floatx4 mfma16(short8 a, short8 b, floatx4 c) {
    return __builtin_amdgcn_mfma_f32_16x16x32_bf16(a, b, c, 0, 0, 0);
}

// ---------------------------------------------------------------------------
// Weight pre-convert: all dense weights -> bf16, (K,N)-major ones transposed
// to (N,K) so every GEMM sees B^T row-major.  196608 elems total.
// Layout (elem offsets): WC0 0 | WC1 16384 | WI 32768 | WH 81920 |
//   M1 131072 | M2 147456 | M3 163840 | R1 172032 | R2 180224 | end 196608
// ---------------------------------------------------------------------------
__global__ __launch_bounds__(256) void k_convert_weights(
    const float* __restrict__ convW, const float* __restrict__ wi, const float* __restrict__ wh,
    const float* __restrict__ m1, const float* __restrict__ m2, const float* __restrict__ m3,
    const float* __restrict__ r1, const float* __restrict__ r2, ushort* __restrict__ W)
{
    int idx = blockIdx.x * 256 + threadIdx.x;
    float v;
    if (idx < 32768) {                      // conv_W[l] (K,N) -> (N,K)
        int l = idx >> 14, t = idx & 16383;
        int n = t >> 7, k = t & 127;
        v = convW[l * 16384 + k * 128 + n];
    } else if (idx < 81920) {               // gru_wi already (N,K)
        v = wi[idx - 32768];
    } else if (idx < 131072) {              // gru_wh already (N,K)
        v = wh[idx - 81920];
    } else if (idx < 147456) { int t = idx - 131072; int n = t >> 7, k = t & 127; v = m1[k * 128 + n]; }
    else if (idx < 163840)   { int t = idx - 147456; int n = t >> 7, k = t & 127; v = m2[k * 128 + n]; }
    else if (idx < 172032)   { int t = idx - 163840; int n = t >> 7, k = t & 127; v = m3[k * 64 + n];  }
    else if (idx < 180224)   { int t = idx - 172032; int n = t >> 6, k = t & 63;  v = r1[k * 128 + n]; }
    else                     { int t = idx - 180224; int n = t >> 7, k = t & 127; v = r2[k * 128 + n]; }
    W[idx] = f2bf(v);
}

// ---------------------------------------------------------------------------
// Elementwise / scatter
// ---------------------------------------------------------------------------
__global__ __launch_bounds__(256) void k_init_x(ushort* __restrict__ X, const float* __restrict__ jvals) {
    int idx = blockIdx.x * 256 + threadIdx.x;          // NTOT*H
    int i = idx >> 7, c = idx & 127;
    float v = 0.f;
    if (i >= N_NODES) {
        int e = i - N_NODES;
        if (c == 0) v = 1.f;
        else if (c == 1) v = jvals[e];
    }
    X[idx] = f2bf(v);
}

// P (fp32): factor rows = x[row]+x[col]; node rows zeroed (scatter adds next)
__global__ __launch_bounds__(256) void k_pre_stage1(float* __restrict__ P, const ushort* __restrict__ X,
                                                    const int* __restrict__ row, const int* __restrict__ col) {
    int idx = blockIdx.x * 256 + threadIdx.x;          // NTOT*H
    int i = idx >> 7, c = idx & 127;
    if (i < N_NODES) { P[idx] = 0.f; return; }
    int e = i - N_NODES;
    P[idx] = bf2f(X[row[e] * H + c]) + bf2f(X[col[e] * H + c]);
}

__global__ __launch_bounds__(256) void k_pre_scatter(float* __restrict__ P, const ushort* __restrict__ X,
                                                     const int* __restrict__ row, const int* __restrict__ col) {
    int idx = blockIdx.x * 256 + threadIdx.x;          // N_EDGES*H
    int e = idx >> 7, c = idx & 127;
    float v = bf2f(X[(size_t)(N_NODES + e) * H + c]);
    atomicAdd(&P[row[e] * H + c], v);
    atomicAdd(&P[col[e] * H + c], v);
}

__global__ __launch_bounds__(256) void k_nm_zero(float* __restrict__ nm) {
    nm[blockIdx.x * 256 + threadIdx.x] = 0.f;          // N_NODES*64
}

__global__ __launch_bounds__(256) void k_nm_scatter(float* __restrict__ nm, const float* __restrict__ msgs,
                                                    const int* __restrict__ row) {
    int idx = blockIdx.x * 256 + threadIdx.x;          // N_EDGES*64
    int e = idx >> 6, c = idx & 63;
    atomicAdd(&nm[row[e] * 64 + c], msgs[idx]);
}

__global__ __launch_bounds__(256) void k_logits(const ushort* __restrict__ hr2, const float* __restrict__ W3,
                                                const float* __restrict__ b3, float* __restrict__ out) {
    int r = blockIdx.x * 4 + (threadIdx.x >> 6);       // one wave per row
    int lane = threadIdx.x & 63;
    float l0 = 0.f, l1 = 0.f;
    for (int k = lane; k < H; k += 64) {
        float hv = bf2f(hr2[(size_t)r * H + k]);
        l0 = fmaf(hv, W3[k * 2 + 0], l0);
        l1 = fmaf(hv, W3[k * 2 + 1], l1);
    }
    for (int off = 32; off; off >>= 1) { l0 += __shfl_down(l0, off); l1 += __shfl_down(l1, off); }
    if (lane == 0) {
        l0 += b3[0]; l1 += b3[1];
        float mx = fmaxf(l0, l1);
        float e0 = __expf(l0 - mx), e1 = __expf(l1 - mx), s = e0 + e1;
        out[r * 2 + 0] = e0 / s;
        out[r * 2 + 1] = e1 / s;
    }
}

// ---------------------------------------------------------------------------
// Generic MFMA GEMM: C[M,N] = act(A[M,K] @ Bt^T + bias), Bt is (N,K) bf16.
// BM=128, BK=32. BN=128: 4 waves on 2x2 grid of 64x64; BN=64: 4 waves x 32 rows.
// AF32: A is fp32 (converted to bf16 during LDS staging), else A is bf16.
// Output row stride = BN (all outputs compact).
// ---------------------------------------------------------------------------
template<int BN, bool AF32, bool RELU, bool OUTF32>
__global__ __launch_bounds__(256) void k_gemm_mfma(
    const void* __restrict__ Aptr, const ushort* __restrict__ Bt,
    const float* __restrict__ bias, void* __restrict__ Cptr, int K, int lda)
{
    constexpr int BM = 128, LDS = 40;                  // 32 + 8 pad (ushort)
    constexpr int MI = (BN == 128) ? 4 : 2;
    constexpr int NI = 4;
    __shared__ ushort As[BM * LDS];
    __shared__ ushort Bs[BN * LDS];
    const int tid = threadIdx.x;
    const size_t row0 = (size_t)blockIdx.x * BM;
    const int w = tid >> 6, lane = tid & 63, quad = lane >> 4, l15 = lane & 15;
    const int wr = (BN == 128) ? (w >> 1) * 64 : w * 32;
    const int wc = (BN == 128) ? (w & 1) * 64 : 0;

    floatx4 acc[MI][NI];
    #pragma unroll
    for (int i = 0; i < MI; ++i)
        #pragma unroll
        for (int j = 0; j < NI; ++j) acc[i][j] = (floatx4)0.f;

    for (int k0 = 0; k0 < K; k0 += 32) {
        __syncthreads();
        if (AF32) {
            const float* A = (const float*)Aptr;
            for (int id = tid; id < BM * 8; id += 256) {
                int m = id >> 3, kc = id & 7;
                float4 v = *(const float4*)(A + (row0 + m) * lda + k0 + kc * 4);
                uint2 u;
                u.x = (uint)f2bf(v.x) | ((uint)f2bf(v.y) << 16);
                u.y = (uint)f2bf(v.z) | ((uint)f2bf(v.w) << 16);
                *(uint2*)&As[m * LDS + kc * 4] = u;
            }
        } else {
            const ushort* A = (const ushort*)Aptr;
            for (int id = tid; id < BM * 4; id += 256) {
                int m = id >> 2, kc = id & 3;
                uint4 v = *(const uint4*)(A + (row0 + m) * (size_t)lda + k0 + kc * 8);
                *(uint2*)&As[m * LDS + kc * 8]     = make_uint2(v.x, v.y);
                *(uint2*)&As[m * LDS + kc * 8 + 4] = make_uint2(v.z, v.w);
            }
        }
        for (int id = tid; id < BN * 4; id += 256) {
            int n = id >> 2, kc = id & 3;
            uint4 v = *(const uint4*)(Bt + (size_t)n * K + k0 + kc * 8);
            *(uint2*)&Bs[n * LDS + kc * 8]     = make_uint2(v.x, v.y);
            *(uint2*)&Bs[n * LDS + kc * 8 + 4] = make_uint2(v.z, v.w);
        }
        __syncthreads();
        short8 a[MI], b[NI];
        #pragma unroll
        for (int mi = 0; mi < MI; ++mi) a[mi] = lds_load8(&As[(wr + mi * 16 + l15) * LDS + quad * 8]);
        #pragma unroll
        for (int ni = 0; ni < NI; ++ni) b[ni] = lds_load8(&Bs[(wc + ni * 16 + l15) * LDS + quad * 8]);
        #pragma unroll
        for (int mi = 0; mi < MI; ++mi)
            #pragma unroll
            for (int ni = 0; ni < NI; ++ni)
                acc[mi][ni] = mfma16(a[mi], b[ni], acc[mi][ni]);
    }

    #pragma unroll
    for (int ni = 0; ni < NI; ++ni) {
        int colc = wc + ni * 16 + l15;
        float bv = bias ? bias[colc] : 0.f;
        #pragma unroll
        for (int mi = 0; mi < MI; ++mi) {
            #pragma unroll
            for (int reg = 0; reg < 4; ++reg) {
                size_t r = row0 + wr + mi * 16 + quad * 4 + reg;
                float v = acc[mi][ni][reg] + bv;
                if (RELU) v = fmaxf(v, 0.f);
                if (OUTF32) ((float*)Cptr)[r * BN + colc] = v;
                else        ((ushort*)Cptr)[r * BN + colc] = f2bf(v);
            }
        }
    }
}

// ---------------------------------------------------------------------------
// Fused GRU: per 32-row block computes rs,zs,i_n,h_n = [AGG|x] @ [wi;wh]^T
// (K=256 effective, 3 active col-groups per half) and applies the GRU update
// to x in place.  No gi/gh intermediate buffers exist.
// ---------------------------------------------------------------------------
__global__ __launch_bounds__(256) void k_gru_fused(
    const ushort* __restrict__ AGG, ushort* __restrict__ X,
    const ushort* __restrict__ WI, const ushort* __restrict__ WH,
    const float* __restrict__ bi, const float* __restrict__ bh)
{
    constexpr int LA = 136;   // 128 + 8 pad
    constexpr int LB = 40;    // 32 + 8 pad
    __shared__ ushort Aagg[32 * LA];
    __shared__ ushort Ax[32 * LA];
    __shared__ ushort Bs[3 * 128 * LB];
    const int tid = threadIdx.x;
    const size_t row0 = (size_t)blockIdx.x * 32;
    const int w = tid >> 6, lane = tid & 63, quad = lane >> 4, l15 = lane & 15;
    const int nc0 = w * 32;   // this wave's 32 output cols

    for (int id = tid; id < 512; id += 256) {          // stage both A halves fully
        int m = id >> 4, c8 = (id & 15) * 8;
        *(uint4*)&Aagg[m * LA + c8] = *(const uint4*)(AGG + (row0 + m) * H + c8);
        *(uint4*)&Ax[m * LA + c8]   = *(const uint4*)(X + (row0 + m) * H + c8);
    }

    floatx4 accR[2][2], accZ[2][2], accN[2][2][2];     // accN[h]: h=0 i_n, h=1 h_n
    #pragma unroll
    for (int i = 0; i < 2; ++i)
        #pragma unroll
        for (int j = 0; j < 2; ++j) {
            accR[i][j] = (floatx4)0.f; accZ[i][j] = (floatx4)0.f;
            accN[0][i][j] = (floatx4)0.f; accN[1][i][j] = (floatx4)0.f;
        }

    for (int h = 0; h < 2; ++h) {
        const ushort* Wsrc = h ? WH : WI;
        const ushort* Asrc = h ? Ax : Aagg;
        for (int k0 = 0; k0 < 128; k0 += 32) {
            __syncthreads();
            for (int id = tid; id < 1536; id += 256) { // Bs[3][128][32]
                int s = id >> 9, rr = (id >> 2) & 127, kc = (id & 3) * 8;
                uint4 v = *(const uint4*)(Wsrc + (size_t)(s * 128 + rr) * H + k0 + kc);
                *(uint2*)&Bs[(s * 128 + rr) * LB + kc]     = make_uint2(v.x, v.y);
                *(uint2*)&Bs[(s * 128 + rr) * LB + kc + 4] = make_uint2(v.z, v.w);
            }
            __syncthreads();
            short8 a[2];
            #pragma unroll
            for (int mi = 0; mi < 2; ++mi)
                a[mi] = lds_load8(&Asrc[(mi * 16 + l15) * LA + k0 + quad * 8]);
            #pragma unroll
            for (int s = 0; s < 3; ++s) {
                short8 bf[2];
                #pragma unroll
                for (int ni = 0; ni < 2; ++ni)
                    bf[ni] = lds_load8(&Bs[(s * 128 + nc0 + ni * 16 + l15) * LB + quad * 8]);
                #pragma unroll
                for (int mi = 0; mi < 2; ++mi)
                    #pragma unroll
                    for (int ni = 0; ni < 2; ++ni) {
                        if (s == 0)      accR[mi][ni]    = mfma16(a[mi], bf[ni], accR[mi][ni]);
                        else if (s == 1) accZ[mi][ni]    = mfma16(a[mi], bf[ni], accZ[mi][ni]);
                        else             accN[h][mi][ni] = mfma16(a[mi], bf[ni], accN[h][mi][ni]);
                    }
            }
        }
    }

    #pragma unroll
    for (int ni = 0; ni < 2; ++ni) {
        int colc = nc0 + ni * 16 + l15;
        float bir = bi[colc], biz = bi[128 + colc], bin = bi[256 + colc];
        float bhr = bh[colc], bhz = bh[128 + colc], bhn = bh[256 + colc];
        #pragma unroll
        for (int mi = 0; mi < 2; ++mi)
            #pragma unroll
            for (int reg = 0; reg < 4; ++reg) {
                int rl = mi * 16 + quad * 4 + reg;
                float rs = accR[mi][ni][reg] + bir + bhr;
                float zs = accZ[mi][ni][reg] + biz + bhz;
                float rr = 1.f / (1.f + __expf(-rs));
                float zz = 1.f / (1.f + __expf(-zs));
                float nn = tanhf(accN[0][mi][ni][reg] + bin + rr * (accN[1][mi][ni][reg] + bhn));
                float xo = bf2f(Ax[rl * LA + colc]);
                X[(row0 + rl) * H + colc] = f2bf((1.f - zz) * nn + zz * xo);
            }
    }
}

// ---------------------------------------------------------------------------
// Launch.  Workspace (bytes):
//   X   bf16 NTOT*128           @ 0           (35,651,584)
//   P   f32  NTOT*128           @ 35,651,584  (71,303,168)  [later: hm1, hm2]
//   AGG bf16 NTOT*128           @ 106,954,752 (35,651,584)  [later: msgs f32]
//   Wbf bf16 196608             @ 142,606,336 (393,216)
//   nm  f32  8192*64            @ 142,999,552 (2,097,152)
//   hr1 bf16 8192*128           @ 145,096,704 (2,097,152)
//   hr2 bf16 8192*128           @ 147,193,856 (2,097,152)
//   total 149,291,008 B  (~149.3 MB)
// ---------------------------------------------------------------------------
extern "C" void kernel_launch(void* const* d_in, const int* in_sizes, int n_in,
                              void* d_out, int out_size, void* d_ws, size_t ws_size,
                              hipStream_t stream) {
    (void)in_sizes; (void)n_in; (void)out_size;
    const float* jvals  = (const float*)d_in[0];
    const int*   row    = (const int*)d_in[2];
    const int*   col    = (const int*)d_in[3];
    const float* conv_W = (const float*)d_in[4];
    const float* gru_wi = (const float*)d_in[5];
    const float* gru_wh = (const float*)d_in[6];
    const float* gru_bi = (const float*)d_in[7];
    const float* gru_bh = (const float*)d_in[8];
    const float* mp_W1  = (const float*)d_in[9];
    const float* mp_b1  = (const float*)d_in[10];
    const float* mp_W2  = (const float*)d_in[11];
    const float* mp_b2  = (const float*)d_in[12];
    const float* mp_W3  = (const float*)d_in[13];
    const float* mp_b3  = (const float*)d_in[14];
    const float* ro_W1  = (const float*)d_in[15];
    const float* ro_b1  = (const float*)d_in[16];
    const float* ro_W2  = (const float*)d_in[17];
    const float* ro_b2  = (const float*)d_in[18];
    const float* ro_W3  = (const float*)d_in[19];
    const float* ro_b3  = (const float*)d_in[20];

    constexpr size_t OFF_P   = (size_t)NTOT * H * 2;
    constexpr size_t OFF_AGG = OFF_P + (size_t)NTOT * H * 4;
    constexpr size_t OFF_W   = OFF_AGG + (size_t)NTOT * H * 2;
    constexpr size_t OFF_NM  = OFF_W + 196608ull * 2;
    constexpr size_t OFF_HR1 = OFF_NM + 8192ull * 64 * 4;
    constexpr size_t OFF_HR2 = OFF_HR1 + 8192ull * 128 * 2;
    constexpr size_t WS_NEED = OFF_HR2 + 8192ull * 128 * 2;
    if (ws_size < WS_NEED) return;   // clean failure instead of device fault

    char* ws = (char*)d_ws;
    ushort* Xb   = (ushort*)ws;
    float*  P    = (float*)(ws + OFF_P);
    ushort* AGG  = (ushort*)(ws + OFF_AGG);
    ushort* Wb   = (ushort*)(ws + OFF_W);
    float*  nm   = (float*)(ws + OFF_NM);
    ushort* hr1  = (ushort*)(ws + OFF_HR1);
    ushort* hr2  = (ushort*)(ws + OFF_HR2);
    ushort* hm1  = (ushort*)(ws + OFF_P);                 // reuse P region
    ushort* hm2  = (ushort*)(ws + OFF_P + 33554432ull);
    float*  msgs = (float*)(ws + OFF_AGG);                // reuse AGG region

    dim3 blk(256);

    k_convert_weights<<<768, blk, 0, stream>>>(conv_W, gru_wi, gru_wh, mp_W1, mp_W2, mp_W3, ro_W1, ro_W2, Wb);
    k_init_x<<<NTOT * H / 256, blk, 0, stream>>>(Xb, jvals);

    for (int l = 0; l < 2; ++l) {
        k_pre_stage1<<<NTOT * H / 256, blk, 0, stream>>>(P, Xb, row, col);
        k_pre_scatter<<<N_EDGES * H / 256, blk, 0, stream>>>(P, Xb, row, col);
        // AGG = P @ conv_W[l]   (A fp32 -> bf16 in staging)
        k_gemm_mfma<128, true, false, false><<<NTOT / 128, blk, 0, stream>>>(
            P, Wb + (size_t)l * 16384, nullptr, AGG, 128, 128);
        k_gru_fused<<<NTOT / 32, blk, 0, stream>>>(AGG, Xb, Wb + 32768, Wb + 81920, gru_bi, gru_bh);
    }

    // edge MLP on factor rows
    k_gemm_mfma<128, false, true, false><<<N_EDGES / 128, blk, 0, stream>>>(
        Xb + (size_t)N_NODES * H, Wb + 131072, mp_b1, hm1, 128, 128);
    k_gemm_mfma<128, false, true, false><<<N_EDGES / 128, blk, 0, stream>>>(
        hm1, Wb + 147456, mp_b2, hm2, 128, 128);
    k_gemm_mfma<64, false, false, true><<<N_EDGES / 128, blk, 0, stream>>>(
        hm2, Wb + 163840, mp_b3, msgs, 128, 128);

    // node_msgs = segment_sum(msgs, row)
    k_nm_zero<<<N_NODES * 64 / 256, blk, 0, stream>>>(nm);
    k_nm_scatter<<<N_EDGES * 64 / 256, blk, 0, stream>>>(nm, msgs, row);

    // readout
    k_gemm_mfma<128, true, true, false><<<N_NODES / 128, blk, 0, stream>>>(
        nm, Wb + 172032, ro_b1, hr1, 64, 64);
    k_gemm_mfma<128, false, true, false><<<N_NODES / 128, blk, 0, stream>>>(
        hr1, Wb + 180224, ro_b2, hr2, 128, 128);
    k_logits<<<N_NODES / 4, blk, 0, stream>>>(hr2, ro_W3, ro_b3, (float*)d_out);
}

// Round 3
// 548.797 us; speedup vs baseline: 1.3883x; 1.3883x over previous
//
#include <hip/hip_runtime.h>
#include <hip/hip_bf16.h>
#include <cstdint>

#define N_NODES 8192
#define N_EDGES 131072
#define NTOT 139264          // N_NODES + N_EDGES
#define H 128

typedef __attribute__((ext_vector_type(8))) short short8;
typedef __attribute__((ext_vector_type(4))) float floatx4;

__device__ __forceinline__ ushort f2bf(float f) {
    union { float f; uint32_t u; } v; v.f = f;
    uint32_t r = v.u + 0x7fffu + ((v.u >> 16) & 1u);   // RNE
    return (ushort)(r >> 16);
}
__device__ __forceinline__ float bf2f(ushort u) {
    union { uint32_t u; float f; } v; v.u = ((uint32_t)u) << 16;
    return v.f;
}
__device__ __forceinline__ float bflo(uint u) { union { uint32_t u; float f; } v; v.u = u << 16; return v.f; }
__device__ __forceinline__ float bfhi(uint u) { union { uint32_t u; float f; } v; v.u = u & 0xffff0000u; return v.f; }
__device__ __forceinline__ uint packbf(float a, float b) { return (uint)f2bf(a) | ((uint)f2bf(b) << 16); }

__device__ __forceinline__ short8 lds_load8(const ushort* p) {
    union { short8 s; uint2 u[2]; } r;
    r.u[0] = *(const uint2*)p;
    r.u[1] = *(const uint2*)(p + 4);
    return r.s;
}
__device__ __forceinline__ floatx4 mfma16(short8 a, short8 b, floatx4 c) {
    return __builtin_amdgcn_mfma_f32_16x16x32_bf16(a, b, c, 0, 0, 0);
}

// ---------------------------------------------------------------------------
// Weight pre-convert -> bf16 (N,K) layouts.  Elem offsets into Wb:
//   [0..32768)   unused (conv folded into Wci)
//   WI 32768 | WH 81920 | M1 131072 | M2 147456 | M3 163840 | R1 172032 |
//   R2 180224 | end 196608
// ---------------------------------------------------------------------------
__global__ __launch_bounds__(256) void k_convert_weights(
    const float* __restrict__ convW, const float* __restrict__ wi, const float* __restrict__ wh,
    const float* __restrict__ m1, const float* __restrict__ m2, const float* __restrict__ m3,
    const float* __restrict__ r1, const float* __restrict__ r2, ushort* __restrict__ W)
{
    int idx = blockIdx.x * 256 + threadIdx.x;
    float v;
    if (idx < 32768) { W[idx] = 0; return; }
    else if (idx < 81920)  v = wi[idx - 32768];
    else if (idx < 131072) v = wh[idx - 81920];
    else if (idx < 147456) { int t = idx - 131072; int n = t >> 7, k = t & 127; v = m1[k * 128 + n]; }
    else if (idx < 163840) { int t = idx - 147456; int n = t >> 7, k = t & 127; v = m2[k * 128 + n]; }
    else if (idx < 172032) { int t = idx - 163840; int n = t >> 7, k = t & 127; v = m3[k * 64 + n];  }
    else if (idx < 180224) { int t = idx - 172032; int n = t >> 6, k = t & 63;  v = r1[k * 128 + n]; }
    else                   { int t = idx - 180224; int n = t >> 7, k = t & 127; v = r2[k * 128 + n]; }
    W[idx] = f2bf(v);
}

// Wci[l][n][k] = sum_j convW[l][k][j] * wi[n][j]   (N=384, K=128), bf16 out
__global__ __launch_bounds__(256) void k_make_wci(
    const float* __restrict__ convW, const float* __restrict__ wi, ushort* __restrict__ Wci)
{
    int idx = blockIdx.x * 256 + threadIdx.x;       // 2*384*128
    int l = idx / 49152, t = idx % 49152;
    int n = t >> 7, k = t & 127;
    const float* wc = convW + l * 16384 + k * 128;
    const float* wr = wi + n * 128;
    float s = 0.f;
    #pragma unroll 8
    for (int j = 0; j < 128; ++j) s = fmaf(wc[j], wr[j], s);
    Wci[idx] = f2bf(s);
}

// ---------------------------------------------------------------------------
// CSR build (incident lists).  Full CSR: node <- both row&col sides (payload e,
// factor row = N_NODES+e).  Row-CSR: node <- row side only (payload e).
// ---------------------------------------------------------------------------
__global__ __launch_bounds__(256) void k_zero_deg(int* __restrict__ deg, int* __restrict__ deg2) {
    int i = blockIdx.x * 256 + threadIdx.x;         // 8192 each
    if (i < 8192) { deg[i] = 0; deg2[i] = 0; }
}

__global__ __launch_bounds__(256) void k_deg_count(const int* __restrict__ row, const int* __restrict__ col,
                                                   int* __restrict__ deg, int* __restrict__ deg2) {
    int e = blockIdx.x * 256 + threadIdx.x;         // N_EDGES
    atomicAdd(&deg[row[e]], 1);
    atomicAdd(&deg[col[e]], 1);
    atomicAdd(&deg2[row[e]], 1);
}

__global__ __launch_bounds__(256) void k_scan(const int* __restrict__ deg, int* __restrict__ start, int* __restrict__ cur,
                                              const int* __restrict__ deg2, int* __restrict__ start2, int* __restrict__ cur2) {
    __shared__ int s1[256], s2[256];
    int tid = threadIdx.x, base = tid * 32;
    int a = 0, b = 0;
    for (int i = 0; i < 32; ++i) { a += deg[base + i]; b += deg2[base + i]; }
    s1[tid] = a; s2[tid] = b;
    __syncthreads();
    if (tid == 0) {
        int acc = 0, acc2 = 0;
        for (int i = 0; i < 256; ++i) {
            int t = s1[i]; s1[i] = acc; acc += t;
            int u = s2[i]; s2[i] = acc2; acc2 += u;
        }
    }
    __syncthreads();
    int off = s1[tid], off2 = s2[tid];
    for (int i = 0; i < 32; ++i) {
        start[base + i] = off;  cur[base + i] = off;   off += deg[base + i];
        start2[base + i] = off2; cur2[base + i] = off2; off2 += deg2[base + i];
    }
}

__global__ __launch_bounds__(256) void k_fill(const int* __restrict__ row, const int* __restrict__ col,
                                              int* __restrict__ cur, int* __restrict__ cur2,
                                              int* __restrict__ list, int* __restrict__ list2) {
    int e = blockIdx.x * 256 + threadIdx.x;         // N_EDGES
    int p = atomicAdd(&cur[row[e]], 1);  list[p] = e;
    int q = atomicAdd(&cur[col[e]], 1);  list[q] = e;
    int r2 = atomicAdd(&cur2[row[e]], 1); list2[r2] = e;
}

// ---------------------------------------------------------------------------
// Elementwise / gather
// ---------------------------------------------------------------------------
__global__ __launch_bounds__(256) void k_init_x(ushort* __restrict__ X, const float* __restrict__ jvals) {
    int idx = blockIdx.x * 256 + threadIdx.x;       // NTOT*H
    int i = idx >> 7, c = idx & 127;
    float v = 0.f;
    if (i >= N_NODES) {
        int e = i - N_NODES;
        if (c == 0) v = 1.f;
        else if (c == 1) v = jvals[e];
    }
    X[idx] = f2bf(v);
}

// P factor rows = X[row[e]] + X[col[e]]   (one wave per edge row, uint = 2 bf16)
__global__ __launch_bounds__(256) void k_agg_factors(uint* __restrict__ P, const uint* __restrict__ X,
                                                     const int* __restrict__ row, const int* __restrict__ col) {
    int idx = blockIdx.x * 256 + threadIdx.x;       // N_EDGES*64
    int e = idx >> 6, l = idx & 63;
    uint a = X[(size_t)row[e] * 64 + l];
    uint b = X[(size_t)col[e] * 64 + l];
    P[(size_t)(N_NODES + e) * 64 + l] = packbf(bflo(a) + bflo(b), bfhi(a) + bfhi(b));
}

// P node rows = sum over incident factor rows (CSR gather, one wave per node)
__global__ __launch_bounds__(256) void k_agg_nodes(uint* __restrict__ P, const uint* __restrict__ X,
                                                   const int* __restrict__ start, const int* __restrict__ deg,
                                                   const int* __restrict__ list) {
    int node = blockIdx.x * 4 + (threadIdx.x >> 6);
    int lane = threadIdx.x & 63;
    int s = start[node], d = deg[node];
    float a0 = 0.f, b0 = 0.f, a1 = 0.f, b1 = 0.f;
    int i = 0;
    for (; i + 1 < d; i += 2) {
        uint v0 = X[(size_t)(N_NODES + list[s + i]) * 64 + lane];
        uint v1 = X[(size_t)(N_NODES + list[s + i + 1]) * 64 + lane];
        a0 += bflo(v0); b0 += bfhi(v0);
        a1 += bflo(v1); b1 += bfhi(v1);
    }
    if (i < d) {
        uint v0 = X[(size_t)(N_NODES + list[s + i]) * 64 + lane];
        a0 += bflo(v0); b0 += bfhi(v0);
    }
    P[(size_t)node * 64 + lane] = packbf(a0 + a1, b0 + b1);
}

// node_msgs = segment_sum(msgs, row) via row-CSR (one wave per node, f32)
__global__ __launch_bounds__(256) void k_nm_gather(float* __restrict__ nm, const float* __restrict__ msgs,
                                                   const int* __restrict__ start2, const int* __restrict__ deg2,
                                                   const int* __restrict__ list2) {
    int node = blockIdx.x * 4 + (threadIdx.x >> 6);
    int lane = threadIdx.x & 63;
    int s = start2[node], d = deg2[node];
    float a0 = 0.f, a1 = 0.f;
    int i = 0;
    for (; i + 1 < d; i += 2) {
        a0 += msgs[(size_t)list2[s + i] * 64 + lane];
        a1 += msgs[(size_t)list2[s + i + 1] * 64 + lane];
    }
    if (i < d) a0 += msgs[(size_t)list2[s + i] * 64 + lane];
    nm[(size_t)node * 64 + lane] = a0 + a1;
}

__global__ __launch_bounds__(256) void k_logits(const ushort* __restrict__ hr2, const float* __restrict__ W3,
                                                const float* __restrict__ b3, float* __restrict__ out) {
    int r = blockIdx.x * 4 + (threadIdx.x >> 6);
    int lane = threadIdx.x & 63;
    float l0 = 0.f, l1 = 0.f;
    for (int k = lane; k < H; k += 64) {
        float hv = bf2f(hr2[(size_t)r * H + k]);
        l0 = fmaf(hv, W3[k * 2 + 0], l0);
        l1 = fmaf(hv, W3[k * 2 + 1], l1);
    }
    for (int off = 32; off; off >>= 1) { l0 += __shfl_down(l0, off); l1 += __shfl_down(l1, off); }
    if (lane == 0) {
        l0 += b3[0]; l1 += b3[1];
        float mx = fmaxf(l0, l1);
        float e0 = __expf(l0 - mx), e1 = __expf(l1 - mx), s = e0 + e1;
        out[r * 2 + 0] = e0 / s;
        out[r * 2 + 1] = e1 / s;
    }
}

// ---------------------------------------------------------------------------
// Generic MFMA GEMM (unchanged from R2): C = act(A @ Bt^T + bias)
// ---------------------------------------------------------------------------
template<int BN, bool AF32, bool RELU, bool OUTF32>
__global__ __launch_bounds__(256) void k_gemm_mfma(
    const void* __restrict__ Aptr, const ushort* __restrict__ Bt,
    const float* __restrict__ bias, void* __restrict__ Cptr, int K, int lda)
{
    constexpr int BM = 128, LDS = 40;
    constexpr int MI = (BN == 128) ? 4 : 2;
    constexpr int NI = 4;
    __shared__ ushort As[BM * LDS];
    __shared__ ushort Bs[BN * LDS];
    const int tid = threadIdx.x;
    const size_t row0 = (size_t)blockIdx.x * BM;
    const int w = tid >> 6, lane = tid & 63, quad = lane >> 4, l15 = lane & 15;
    const int wr = (BN == 128) ? (w >> 1) * 64 : w * 32;
    const int wc = (BN == 128) ? (w & 1) * 64 : 0;

    floatx4 acc[MI][NI];
    #pragma unroll
    for (int i = 0; i < MI; ++i)
        #pragma unroll
        for (int j = 0; j < NI; ++j) acc[i][j] = (floatx4)0.f;

    for (int k0 = 0; k0 < K; k0 += 32) {
        __syncthreads();
        if (AF32) {
            const float* A = (const float*)Aptr;
            for (int id = tid; id < BM * 8; id += 256) {
                int m = id >> 3, kc = id & 7;
                float4 v = *(const float4*)(A + (row0 + m) * lda + k0 + kc * 4);
                uint2 u;
                u.x = (uint)f2bf(v.x) | ((uint)f2bf(v.y) << 16);
                u.y = (uint)f2bf(v.z) | ((uint)f2bf(v.w) << 16);
                *(uint2*)&As[m * LDS + kc * 4] = u;
            }
        } else {
            const ushort* A = (const ushort*)Aptr;
            for (int id = tid; id < BM * 4; id += 256) {
                int m = id >> 2, kc = id & 3;
                uint4 v = *(const uint4*)(A + (row0 + m) * (size_t)lda + k0 + kc * 8);
                *(uint2*)&As[m * LDS + kc * 8]     = make_uint2(v.x, v.y);
                *(uint2*)&As[m * LDS + kc * 8 + 4] = make_uint2(v.z, v.w);
            }
        }
        for (int id = tid; id < BN * 4; id += 256) {
            int n = id >> 2, kc = id & 3;
            uint4 v = *(const uint4*)(Bt + (size_t)n * K + k0 + kc * 8);
            *(uint2*)&Bs[n * LDS + kc * 8]     = make_uint2(v.x, v.y);
            *(uint2*)&Bs[n * LDS + kc * 8 + 4] = make_uint2(v.z, v.w);
        }
        __syncthreads();
        short8 a[MI], b[NI];
        #pragma unroll
        for (int mi = 0; mi < MI; ++mi) a[mi] = lds_load8(&As[(wr + mi * 16 + l15) * LDS + quad * 8]);
        #pragma unroll
        for (int ni = 0; ni < NI; ++ni) b[ni] = lds_load8(&Bs[(wc + ni * 16 + l15) * LDS + quad * 8]);
        #pragma unroll
        for (int mi = 0; mi < MI; ++mi)
            #pragma unroll
            for (int ni = 0; ni < NI; ++ni)
                acc[mi][ni] = mfma16(a[mi], b[ni], acc[mi][ni]);
    }

    #pragma unroll
    for (int ni = 0; ni < NI; ++ni) {
        int colc = wc + ni * 16 + l15;
        float bv = bias ? bias[colc] : 0.f;
        #pragma unroll
        for (int mi = 0; mi < MI; ++mi) {
            #pragma unroll
            for (int reg = 0; reg < 4; ++reg) {
                size_t r = row0 + wr + mi * 16 + quad * 4 + reg;
                float v = acc[mi][ni][reg] + bv;
                if (RELU) v = fmaxf(v, 0.f);
                if (OUTF32) ((float*)Cptr)[r * BN + colc] = v;
                else        ((ushort*)Cptr)[r * BN + colc] = f2bf(v);
            }
        }
    }
}

// ---------------------------------------------------------------------------
// Fused GRU v2 (BM=64): gates_i = P @ WCI_s^T, gates_h = X @ WH_s^T (K=128),
// GRU update applied in-register, X written in place.
// ---------------------------------------------------------------------------
__global__ __launch_bounds__(256) void k_gru2(
    const ushort* __restrict__ P, ushort* __restrict__ X,
    const ushort* __restrict__ WCI, const ushort* __restrict__ WH,
    const float* __restrict__ bi, const float* __restrict__ bh)
{
    constexpr int LA = 136;   // 128 + 8 pad (ushort)
    constexpr int LB = 40;    // 32 + 8 pad
    __shared__ ushort Ap[64 * LA];
    __shared__ ushort Ax[64 * LA];
    __shared__ ushort Bs[384 * LB];
    const int tid = threadIdx.x;
    const size_t row0 = (size_t)blockIdx.x * 64;
    const int w = tid >> 6, lane = tid & 63, quad = lane >> 4, l15 = lane & 15;
    const int nc0 = w * 32;   // this wave's 32 output cols

    for (int id = tid; id < 1024; id += 256) {        // stage A tiles (64 x 128)
        int m = id >> 4, c8 = (id & 15) * 8;
        *(uint4*)&Ap[m * LA + c8] = *(const uint4*)(P + (row0 + m) * H + c8);
        *(uint4*)&Ax[m * LA + c8] = *(const uint4*)(X + (row0 + m) * H + c8);
    }

    floatx4 accR[4][2], accZ[4][2], accI[4][2], accHN[4][2];
    #pragma unroll
    for (int i = 0; i < 4; ++i)
        #pragma unroll
        for (int j = 0; j < 2; ++j) {
            accR[i][j] = (floatx4)0.f; accZ[i][j] = (floatx4)0.f;
            accI[i][j] = (floatx4)0.f; accHN[i][j] = (floatx4)0.f;
        }

    for (int h = 0; h < 2; ++h) {
        const ushort* Wsrc = h ? WH : WCI;
        const ushort* Asrc = h ? Ax : Ap;
        for (int k0 = 0; k0 < 128; k0 += 32) {
            __syncthreads();
            for (int id = tid; id < 1536; id += 256) { // Bs[384][32]
                int n = id >> 2, kc = (id & 3) * 8;
                *(uint4*)&Bs[n * LB + kc] = *(const uint4*)(Wsrc + (size_t)n * H + k0 + kc);
            }
            __syncthreads();
            short8 a[4];
            #pragma unroll
            for (int mi = 0; mi < 4; ++mi)
                a[mi] = lds_load8(&Asrc[(mi * 16 + l15) * LA + k0 + quad * 8]);
            #pragma unroll
            for (int s = 0; s < 3; ++s) {
                short8 bf[2];
                #pragma unroll
                for (int ni = 0; ni < 2; ++ni)
                    bf[ni] = lds_load8(&Bs[(s * 128 + nc0 + ni * 16 + l15) * LB + quad * 8]);
                #pragma unroll
                for (int mi = 0; mi < 4; ++mi)
                    #pragma unroll
                    for (int ni = 0; ni < 2; ++ni) {
                        if (s == 0)      accR[mi][ni] = mfma16(a[mi], bf[ni], accR[mi][ni]);
                        else if (s == 1) accZ[mi][ni] = mfma16(a[mi], bf[ni], accZ[mi][ni]);
                        else if (h == 0) accI[mi][ni] = mfma16(a[mi], bf[ni], accI[mi][ni]);
                        else             accHN[mi][ni] = mfma16(a[mi], bf[ni], accHN[mi][ni]);
                    }
            }
        }
    }

    #pragma unroll
    for (int ni = 0; ni < 2; ++ni) {
        int colc = nc0 + ni * 16 + l15;
        float bir = bi[colc], biz = bi[128 + colc], bin = bi[256 + colc];
        float bhr = bh[colc], bhz = bh[128 + colc], bhn = bh[256 + colc];
        #pragma unroll
        for (int mi = 0; mi < 4; ++mi)
            #pragma unroll
            for (int reg = 0; reg < 4; ++reg) {
                int rl = mi * 16 + quad * 4 + reg;
                float rs = accR[mi][ni][reg] + bir + bhr;
                float zs = accZ[mi][ni][reg] + biz + bhz;
                float rr = 1.f / (1.f + __expf(-rs));
                float zz = 1.f / (1.f + __expf(-zs));
                float nn = tanhf(accI[mi][ni][reg] + bin + rr * (accHN[mi][ni][reg] + bhn));
                float xo = bf2f(Ax[rl * LA + colc]);
                X[(row0 + rl) * H + colc] = f2bf((1.f - zz) * nn + zz * xo);
            }
    }
}

// ---------------------------------------------------------------------------
// Launch.  Workspace layout (bytes):
//   X    bf16 NTOT*128     @ 0            (35,651,584)
//   P    bf16 NTOT*128     @ 35,651,584   (35,651,584)  [later hm1]
//   HM2  bf16 131072*128   @ 71,303,168   (33,554,432)
//   MSGS f32  131072*64    @ 104,857,600  (33,554,432)
//   Wb   bf16 196608       @ 138,412,032  (393,216)
//   WCI  bf16 2*384*128    @ 138,805,248  (196,608)
//   NM   f32  8192*64      @ 139,001,856  (2,097,152)
//   HR1  bf16 8192*128     @ 141,099,008  (2,097,152)
//   HR2  bf16 8192*128     @ 143,196,160  (2,097,152)
//   CSR ints               @ 145,293,312  (196,608: deg,start,cur,deg2,start2,cur2)
//   LIST int 262144        @ 145,489,920  (1,048,576)
//   LIST2 int 131072       @ 146,538,496  (524,288)
//   total 147,062,784 B
// ---------------------------------------------------------------------------
extern "C" void kernel_launch(void* const* d_in, const int* in_sizes, int n_in,
                              void* d_out, int out_size, void* d_ws, size_t ws_size,
                              hipStream_t stream) {
    (void)in_sizes; (void)n_in; (void)out_size;
    const float* jvals  = (const float*)d_in[0];
    const int*   row    = (const int*)d_in[2];
    const int*   col    = (const int*)d_in[3];
    const float* conv_W = (const float*)d_in[4];
    const float* gru_wi = (const float*)d_in[5];
    const float* gru_wh = (const float*)d_in[6];
    const float* gru_bi = (const float*)d_in[7];
    const float* gru_bh = (const float*)d_in[8];
    const float* mp_W1  = (const float*)d_in[9];
    const float* mp_b1  = (const float*)d_in[10];
    const float* mp_W2  = (const float*)d_in[11];
    const float* mp_b2  = (const float*)d_in[12];
    const float* mp_W3  = (const float*)d_in[13];
    const float* mp_b3  = (const float*)d_in[14];
    const float* ro_b1  = (const float*)d_in[16];
    const float* ro_b2  = (const float*)d_in[18];
    const float* ro_W3  = (const float*)d_in[19];
    const float* ro_b3  = (const float*)d_in[20];

    constexpr size_t OFF_P    = 35651584ull;
    constexpr size_t OFF_HM2  = 71303168ull;
    constexpr size_t OFF_MSGS = 104857600ull;
    constexpr size_t OFF_W    = 138412032ull;
    constexpr size_t OFF_WCI  = 138805248ull;
    constexpr size_t OFF_NM   = 139001856ull;
    constexpr size_t OFF_HR1  = 141099008ull;
    constexpr size_t OFF_HR2  = 143196160ull;
    constexpr size_t OFF_CSR  = 145293312ull;
    constexpr size_t OFF_L1   = 145489920ull;
    constexpr size_t OFF_L2   = 146538496ull;
    constexpr size_t WS_NEED  = 147062784ull;
    if (ws_size < WS_NEED) return;

    char* ws = (char*)d_ws;
    ushort* Xb   = (ushort*)ws;
    ushort* P    = (ushort*)(ws + OFF_P);
    ushort* hm1  = (ushort*)(ws + OFF_P);
    ushort* hm2  = (ushort*)(ws + OFF_HM2);
    float*  msgs = (float*)(ws + OFF_MSGS);
    ushort* Wb   = (ushort*)(ws + OFF_W);
    ushort* Wci  = (ushort*)(ws + OFF_WCI);
    float*  nm   = (float*)(ws + OFF_NM);
    ushort* hr1  = (ushort*)(ws + OFF_HR1);
    ushort* hr2  = (ushort*)(ws + OFF_HR2);
    int* deg    = (int*)(ws + OFF_CSR);
    int* start  = deg + 8192;
    int* cur    = deg + 16384;
    int* deg2   = deg + 24576;
    int* start2 = deg + 32768;
    int* cur2   = deg + 40960;
    int* list   = (int*)(ws + OFF_L1);
    int* list2  = (int*)(ws + OFF_L2);

    dim3 blk(256);

    k_convert_weights<<<768, blk, 0, stream>>>(conv_W, gru_wi, gru_wh, mp_W1, mp_W2, mp_W3,
                                               (const float*)d_in[15], (const float*)d_in[17], Wb);
    k_make_wci<<<384, blk, 0, stream>>>(conv_W, gru_wi, Wci);
    k_init_x<<<NTOT * H / 256, blk, 0, stream>>>(Xb, jvals);
    k_zero_deg<<<32, blk, 0, stream>>>(deg, deg2);
    k_deg_count<<<N_EDGES / 256, blk, 0, stream>>>(row, col, deg, deg2);
    k_scan<<<1, blk, 0, stream>>>(deg, start, cur, deg2, start2, cur2);
    k_fill<<<N_EDGES / 256, blk, 0, stream>>>(row, col, cur, cur2, list, list2);

    for (int l = 0; l < 2; ++l) {
        k_agg_factors<<<N_EDGES * 64 / 256, blk, 0, stream>>>((uint*)P, (const uint*)Xb, row, col);
        k_agg_nodes<<<N_NODES / 4, blk, 0, stream>>>((uint*)P, (const uint*)Xb, start, deg, list);
        k_gru2<<<NTOT / 64, blk, 0, stream>>>(P, Xb, Wci + (size_t)l * 49152, Wb + 81920, gru_bi, gru_bh);
    }

    // edge MLP on factor rows
    k_gemm_mfma<128, false, true, false><<<N_EDGES / 128, blk, 0, stream>>>(
        Xb + (size_t)N_NODES * H, Wb + 131072, mp_b1, hm1, 128, 128);
    k_gemm_mfma<128, false, true, false><<<N_EDGES / 128, blk, 0, stream>>>(
        hm1, Wb + 147456, mp_b2, hm2, 128, 128);
    k_gemm_mfma<64, false, false, true><<<N_EDGES / 128, blk, 0, stream>>>(
        hm2, Wb + 163840, mp_b3, msgs, 128, 128);

    // node_msgs = segment_sum(msgs, row)  (row-CSR gather)
    k_nm_gather<<<N_NODES / 4, blk, 0, stream>>>(nm, msgs, start2, deg2, list2);

    // readout
    k_gemm_mfma<128, true, true, false><<<N_NODES / 128, blk, 0, stream>>>(
        nm, Wb + 172032, ro_b1, hr1, 64, 64);
    k_gemm_mfma<128, false, true, false><<<N_NODES / 128, blk, 0, stream>>>(
        hr1, Wb + 180224, ro_b2, hr2, 128, 128);
    k_logits<<<N_NODES / 4, blk, 0, stream>>>(hr2, ro_W3, ro_b3, (float*)d_out);
}

// Round 4
// 504.297 us; speedup vs baseline: 1.5108x; 1.0882x over previous
//
#include <hip/hip_runtime.h>
#include <hip/hip_bf16.h>
#include <cstdint>

#define N_NODES 8192
#define N_EDGES 131072
#define NTOT 139264          // N_NODES + N_EDGES
#define H 128

typedef __attribute__((ext_vector_type(8))) short short8;
typedef __attribute__((ext_vector_type(4))) float floatx4;

__device__ __forceinline__ ushort f2bf(float f) {
    union { float f; uint32_t u; } v; v.f = f;
    uint32_t r = v.u + 0x7fffu + ((v.u >> 16) & 1u);   // RNE
    return (ushort)(r >> 16);
}
__device__ __forceinline__ float bf2f(ushort u) {
    union { uint32_t u; float f; } v; v.u = ((uint32_t)u) << 16;
    return v.f;
}
__device__ __forceinline__ float bflo(uint u) { union { uint32_t u; float f; } v; v.u = u << 16; return v.f; }
__device__ __forceinline__ float bfhi(uint u) { union { uint32_t u; float f; } v; v.u = u & 0xffff0000u; return v.f; }
__device__ __forceinline__ uint packbf(float a, float b) { return (uint)f2bf(a) | ((uint)f2bf(b) << 16); }

__device__ __forceinline__ short8 lds_load8(const ushort* p) {
    union { short8 s; uint2 u[2]; } r;
    r.u[0] = *(const uint2*)p;
    r.u[1] = *(const uint2*)(p + 4);
    return r.s;
}
__device__ __forceinline__ short8 glb_load8(const ushort* p) {
    union { short8 s; uint4 u; } r;
    r.u = *(const uint4*)p;
    return r.s;
}
__device__ __forceinline__ floatx4 mfma16(short8 a, short8 b, floatx4 c) {
    return __builtin_amdgcn_mfma_f32_16x16x32_bf16(a, b, c, 0, 0, 0);
}

// ---------------------------------------------------------------------------
// Weight pre-convert -> bf16 (N,K).  Elem offsets into Wb:
//   WI 32768 (unused region [0,32768) zeroed) | WH 81920 | M1 131072 |
//   M2 147456 | M3 163840 | R1 172032 | R2 180224 | end 196608
// ---------------------------------------------------------------------------
__global__ __launch_bounds__(256) void k_convert_weights(
    const float* __restrict__ convW, const float* __restrict__ wi, const float* __restrict__ wh,
    const float* __restrict__ m1, const float* __restrict__ m2, const float* __restrict__ m3,
    const float* __restrict__ r1, const float* __restrict__ r2, ushort* __restrict__ W)
{
    int idx = blockIdx.x * 256 + threadIdx.x;
    float v;
    if (idx < 32768) { W[idx] = 0; return; }
    else if (idx < 81920)  v = wi[idx - 32768];
    else if (idx < 131072) v = wh[idx - 81920];
    else if (idx < 147456) { int t = idx - 131072; int n = t >> 7, k = t & 127; v = m1[k * 128 + n]; }
    else if (idx < 163840) { int t = idx - 147456; int n = t >> 7, k = t & 127; v = m2[k * 128 + n]; }
    else if (idx < 172032) { int t = idx - 163840; int n = t >> 7, k = t & 127; v = m3[k * 64 + n];  }
    else if (idx < 180224) { int t = idx - 172032; int n = t >> 6, k = t & 63;  v = r1[k * 128 + n]; }
    else                   { int t = idx - 180224; int n = t >> 7, k = t & 127; v = r2[k * 128 + n]; }
    W[idx] = f2bf(v);
}

// Wci[l][n][k] = sum_j convW[l][k][j] * wi[n][j]   (N=384, K=128), bf16 out
__global__ __launch_bounds__(256) void k_make_wci(
    const float* __restrict__ convW, const float* __restrict__ wi, ushort* __restrict__ Wci)
{
    int idx = blockIdx.x * 256 + threadIdx.x;       // 2*384*128
    int l = idx / 49152, t = idx % 49152;
    int n = t >> 7, k = t & 127;
    const float* wc = convW + l * 16384 + k * 128;
    const float* wr = wi + n * 128;
    float s = 0.f;
    #pragma unroll 8
    for (int j = 0; j < 128; ++j) s = fmaf(wc[j], wr[j], s);
    Wci[idx] = f2bf(s);
}

// ---------------------------------------------------------------------------
// CSR build
// ---------------------------------------------------------------------------
__global__ __launch_bounds__(256) void k_zero_deg(int* __restrict__ deg, int* __restrict__ deg2) {
    int i = blockIdx.x * 256 + threadIdx.x;
    if (i < 8192) { deg[i] = 0; deg2[i] = 0; }
}

__global__ __launch_bounds__(256) void k_deg_count(const int* __restrict__ row, const int* __restrict__ col,
                                                   int* __restrict__ deg, int* __restrict__ deg2) {
    int e = blockIdx.x * 256 + threadIdx.x;
    atomicAdd(&deg[row[e]], 1);
    atomicAdd(&deg[col[e]], 1);
    atomicAdd(&deg2[row[e]], 1);
}

__global__ __launch_bounds__(256) void k_scan(const int* __restrict__ deg, int* __restrict__ start, int* __restrict__ cur,
                                              const int* __restrict__ deg2, int* __restrict__ start2, int* __restrict__ cur2) {
    __shared__ int s1[256], s2[256];
    int tid = threadIdx.x, base = tid * 32;
    int a = 0, b = 0;
    for (int i = 0; i < 32; ++i) { a += deg[base + i]; b += deg2[base + i]; }
    s1[tid] = a; s2[tid] = b;
    __syncthreads();
    if (tid == 0) {
        int acc = 0, acc2 = 0;
        for (int i = 0; i < 256; ++i) {
            int t = s1[i]; s1[i] = acc; acc += t;
            int u = s2[i]; s2[i] = acc2; acc2 += u;
        }
    }
    __syncthreads();
    int off = s1[tid], off2 = s2[tid];
    for (int i = 0; i < 32; ++i) {
        start[base + i] = off;  cur[base + i] = off;   off += deg[base + i];
        start2[base + i] = off2; cur2[base + i] = off2; off2 += deg2[base + i];
    }
}

__global__ __launch_bounds__(256) void k_fill(const int* __restrict__ row, const int* __restrict__ col,
                                              int* __restrict__ cur, int* __restrict__ cur2,
                                              int* __restrict__ list, int* __restrict__ list2) {
    int e = blockIdx.x * 256 + threadIdx.x;
    int p = atomicAdd(&cur[row[e]], 1);  list[p] = e;
    int q = atomicAdd(&cur[col[e]], 1);  list[q] = e;
    int r2 = atomicAdd(&cur2[row[e]], 1); list2[r2] = e;
}

// ---------------------------------------------------------------------------
// Elementwise / gather
// ---------------------------------------------------------------------------
__global__ __launch_bounds__(256) void k_init_x(ushort* __restrict__ X, const float* __restrict__ jvals) {
    int idx = blockIdx.x * 256 + threadIdx.x;
    int i = idx >> 7, c = idx & 127;
    float v = 0.f;
    if (i >= N_NODES) {
        int e = i - N_NODES;
        if (c == 0) v = 1.f;
        else if (c == 1) v = jvals[e];
    }
    X[idx] = f2bf(v);
}

__global__ __launch_bounds__(256) void k_agg_factors(uint* __restrict__ P, const uint* __restrict__ X,
                                                     const int* __restrict__ row, const int* __restrict__ col) {
    int idx = blockIdx.x * 256 + threadIdx.x;
    int e = idx >> 6, l = idx & 63;
    uint a = X[(size_t)row[e] * 64 + l];
    uint b = X[(size_t)col[e] * 64 + l];
    P[(size_t)(N_NODES + e) * 64 + l] = packbf(bflo(a) + bflo(b), bfhi(a) + bfhi(b));
}

__global__ __launch_bounds__(256) void k_agg_nodes(uint* __restrict__ P, const uint* __restrict__ X,
                                                   const int* __restrict__ start, const int* __restrict__ deg,
                                                   const int* __restrict__ list) {
    int node = blockIdx.x * 4 + (threadIdx.x >> 6);
    int lane = threadIdx.x & 63;
    int s = start[node], d = deg[node];
    float a0 = 0.f, b0 = 0.f, a1 = 0.f, b1 = 0.f;
    int i = 0;
    for (; i + 1 < d; i += 2) {
        uint v0 = X[(size_t)(N_NODES + list[s + i]) * 64 + lane];
        uint v1 = X[(size_t)(N_NODES + list[s + i + 1]) * 64 + lane];
        a0 += bflo(v0); b0 += bfhi(v0);
        a1 += bflo(v1); b1 += bfhi(v1);
    }
    if (i < d) {
        uint v0 = X[(size_t)(N_NODES + list[s + i]) * 64 + lane];
        a0 += bflo(v0); b0 += bfhi(v0);
    }
    P[(size_t)node * 64 + lane] = packbf(a0 + a1, b0 + b1);
}

// node_msgs = segment_sum(msgs, row) via row-CSR; msgs now bf16
__global__ __launch_bounds__(256) void k_nm_gather(float* __restrict__ nm, const ushort* __restrict__ msgs,
                                                   const int* __restrict__ start2, const int* __restrict__ deg2,
                                                   const int* __restrict__ list2) {
    int node = blockIdx.x * 4 + (threadIdx.x >> 6);
    int lane = threadIdx.x & 63;
    int s = start2[node], d = deg2[node];
    float a0 = 0.f, a1 = 0.f;
    int i = 0;
    for (; i + 1 < d; i += 2) {
        a0 += bf2f(msgs[(size_t)list2[s + i] * 64 + lane]);
        a1 += bf2f(msgs[(size_t)list2[s + i + 1] * 64 + lane]);
    }
    if (i < d) a0 += bf2f(msgs[(size_t)list2[s + i] * 64 + lane]);
    nm[(size_t)node * 64 + lane] = a0 + a1;
}

__global__ __launch_bounds__(256) void k_logits(const ushort* __restrict__ hr2, const float* __restrict__ W3,
                                                const float* __restrict__ b3, float* __restrict__ out) {
    int r = blockIdx.x * 4 + (threadIdx.x >> 6);
    int lane = threadIdx.x & 63;
    float l0 = 0.f, l1 = 0.f;
    for (int k = lane; k < H; k += 64) {
        float hv = bf2f(hr2[(size_t)r * H + k]);
        l0 = fmaf(hv, W3[k * 2 + 0], l0);
        l1 = fmaf(hv, W3[k * 2 + 1], l1);
    }
    for (int off = 32; off; off >>= 1) { l0 += __shfl_down(l0, off); l1 += __shfl_down(l1, off); }
    if (lane == 0) {
        l0 += b3[0]; l1 += b3[1];
        float mx = fmaxf(l0, l1);
        float e0 = __expf(l0 - mx), e1 = __expf(l1 - mx), s = e0 + e1;
        out[r * 2 + 0] = e0 / s;
        out[r * 2 + 1] = e1 / s;
    }
}

// ---------------------------------------------------------------------------
// MFMA GEMM v2: full A+B tiles staged ONCE, single barrier, then pure
// ds_read+MFMA K-loop.  B staged column-permuted so slot ni*16+j holds global
// col base64 + 4*j + ni -> epilogue lane holds 4 consecutive cols.
// C[M,BN] = act(A[M,K] @ Bt^T + bias).  N == BN, K in {64,128}, BM=128.
// ---------------------------------------------------------------------------
template<int BN, bool AF32, bool RELU, bool OUTF32>
__global__ __launch_bounds__(256) void k_gemm2(
    const void* __restrict__ Aptr, const ushort* __restrict__ Bt,
    const float* __restrict__ bias, void* __restrict__ Cptr, int K, int lda)
{
    constexpr int BM = 128, LK = 136;
    constexpr int MI = (BN == 128) ? 4 : 2;
    constexpr int NI = 4;
    __shared__ ushort As[BM * LK];
    __shared__ ushort Bs[BN * LK];
    const int tid = threadIdx.x;
    const size_t row0 = (size_t)blockIdx.x * BM;
    const int kpc = K >> 3;                 // 8-half chunks per row

    if (AF32) {
        const float* A = (const float*)Aptr;
        for (int id = tid; id < BM * kpc; id += 256) {
            int m = id / kpc, kc = id - m * kpc;
            float4 v0 = *(const float4*)(A + (row0 + m) * lda + kc * 8);
            float4 v1 = *(const float4*)(A + (row0 + m) * lda + kc * 8 + 4);
            uint4 u;
            u.x = packbf(v0.x, v0.y); u.y = packbf(v0.z, v0.w);
            u.z = packbf(v1.x, v1.y); u.w = packbf(v1.z, v1.w);
            *(uint4*)&As[m * LK + kc * 8] = u;
        }
    } else {
        const ushort* A = (const ushort*)Aptr;
        for (int id = tid; id < BM * kpc; id += 256) {
            int m = id / kpc, kc = id - m * kpc;
            *(uint4*)&As[m * LK + kc * 8] = *(const uint4*)(A + (row0 + m) * (size_t)lda + kc * 8);
        }
    }
    for (int id = tid; id < BN * kpc; id += 256) {
        int slot = id / kpc, kc = id - slot * kpc;
        int gcol = (slot & ~63) + 4 * (slot & 15) + ((slot >> 4) & 3);
        *(uint4*)&Bs[slot * LK + kc * 8] = *(const uint4*)(Bt + (size_t)gcol * K + kc * 8);
    }
    __syncthreads();

    const int w = tid >> 6, lane = tid & 63, quad = lane >> 4, l15 = lane & 15;
    const int wr = (BN == 128) ? (w >> 1) * 64 : w * 32;
    const int wc = (BN == 128) ? (w & 1) * 64 : 0;

    floatx4 acc[MI][NI];
    #pragma unroll
    for (int i = 0; i < MI; ++i)
        #pragma unroll
        for (int j = 0; j < NI; ++j) acc[i][j] = (floatx4)0.f;

    for (int k0 = 0; k0 < K; k0 += 32) {
        short8 a[MI], b[NI];
        #pragma unroll
        for (int mi = 0; mi < MI; ++mi) a[mi] = lds_load8(&As[(wr + mi * 16 + l15) * LK + k0 + quad * 8]);
        #pragma unroll
        for (int ni = 0; ni < NI; ++ni) b[ni] = lds_load8(&Bs[(wc + ni * 16 + l15) * LK + k0 + quad * 8]);
        #pragma unroll
        for (int mi = 0; mi < MI; ++mi)
            #pragma unroll
            for (int ni = 0; ni < NI; ++ni)
                acc[mi][ni] = mfma16(a[mi], b[ni], acc[mi][ni]);
    }

    float bv[NI];
    #pragma unroll
    for (int ni = 0; ni < NI; ++ni) bv[ni] = bias ? bias[wc + 4 * l15 + ni] : 0.f;
    #pragma unroll
    for (int mi = 0; mi < MI; ++mi) {
        #pragma unroll
        for (int reg = 0; reg < 4; ++reg) {
            size_t r = row0 + wr + mi * 16 + quad * 4 + reg;
            float v[NI];
            #pragma unroll
            for (int ni = 0; ni < NI; ++ni) {
                v[ni] = acc[mi][ni][reg] + bv[ni];
                if (RELU) v[ni] = fmaxf(v[ni], 0.f);
            }
            if (OUTF32) {
                float4 o = make_float4(v[0], v[1], v[2], v[3]);
                *(float4*)((float*)Cptr + r * BN + wc + 4 * l15) = o;
            } else {
                uint2 o = make_uint2(packbf(v[0], v[1]), packbf(v[2], v[3]));
                *(uint2*)((ushort*)Cptr + r * BN + wc + 4 * l15) = o;
            }
        }
    }
}

// ---------------------------------------------------------------------------
// Fused GRU v3: grid (4 col-groups, NTOT/256).  Block stages its 32 c-cols'
// weights (WCI+WH, 3 gates) ONCE (52 KB LDS); waves then process 64 rows each
// with A-frags loaded directly from global (L2/L3-hot) -- no barriers in the
// K-loop.  Column-permuted weight slots: slot ni*16+j <-> col c0 + 2*j + ni,
// so the epilogue writes X as packed uint pairs.  Xin -> Xout (ping-pong).
// ---------------------------------------------------------------------------
__global__ __launch_bounds__(256, 2) void k_gru3(
    const ushort* __restrict__ P, const ushort* __restrict__ Xin, ushort* __restrict__ Xout,
    const ushort* __restrict__ WCI, const ushort* __restrict__ WH,
    const float* __restrict__ bi, const float* __restrict__ bh)
{
    constexpr int LK = 136;
    __shared__ ushort Ws[6 * 32 * LK];     // [h*3+s][slot][k]
    const int tid = threadIdx.x;
    const int c0 = blockIdx.x * 32;
    const size_t brow0 = (size_t)blockIdx.y * 256;

    for (int id = tid; id < 3072; id += 256) {       // 6*32*16 uint4 chunks
        int kc = id & 15;
        int slot = (id >> 4) & 31;
        int g = id >> 9;                             // h*3+s
        int h = g / 3, s = g - h * 3;
        int gcol = c0 + 2 * (slot & 15) + (slot >> 4);
        const ushort* src = (h ? WH : WCI) + ((size_t)(s * 128 + gcol)) * 128 + kc * 8;
        *(uint4*)&Ws[(g * 32 + slot) * LK + kc * 8] = *(const uint4*)src;
    }
    __syncthreads();

    const int w = tid >> 6, lane = tid & 63, quad = lane >> 4, l15 = lane & 15;
    const size_t row0 = brow0 + w * 64;

    floatx4 accR[4][2], accZ[4][2], accI[4][2], accHN[4][2];
    #pragma unroll
    for (int i = 0; i < 4; ++i)
        #pragma unroll
        for (int j = 0; j < 2; ++j) {
            accR[i][j] = (floatx4)0.f; accZ[i][j] = (floatx4)0.f;
            accI[i][j] = (floatx4)0.f; accHN[i][j] = (floatx4)0.f;
        }

    #pragma unroll
    for (int h = 0; h < 2; ++h) {
        const ushort* Ah = h ? Xin : P;
        #pragma unroll
        for (int k4 = 0; k4 < 4; ++k4) {
            const int k0 = k4 * 32;
            short8 a[4];
            #pragma unroll
            for (int mi = 0; mi < 4; ++mi)
                a[mi] = glb_load8(Ah + (row0 + mi * 16 + l15) * H + k0 + quad * 8);
            #pragma unroll
            for (int s = 0; s < 3; ++s) {
                short8 b[2];
                #pragma unroll
                for (int ni = 0; ni < 2; ++ni)
                    b[ni] = lds_load8(&Ws[((h * 3 + s) * 32 + ni * 16 + l15) * LK + k0 + quad * 8]);
                #pragma unroll
                for (int mi = 0; mi < 4; ++mi)
                    #pragma unroll
                    for (int ni = 0; ni < 2; ++ni) {
                        if (s == 0)      accR[mi][ni] = mfma16(a[mi], b[ni], accR[mi][ni]);
                        else if (s == 1) accZ[mi][ni] = mfma16(a[mi], b[ni], accZ[mi][ni]);
                        else if (h == 0) accI[mi][ni] = mfma16(a[mi], b[ni], accI[mi][ni]);
                        else             accHN[mi][ni] = mfma16(a[mi], b[ni], accHN[mi][ni]);
                    }
            }
        }
    }

    // epilogue: lane holds cols (c0+2*l15, c0+2*l15+1) = one uint of Xin/Xout
    const int ce = c0 + 2 * l15;
    float bir[2], biz[2], bin_[2], bhr[2], bhz[2], bhn[2];
    #pragma unroll
    for (int ni = 0; ni < 2; ++ni) {
        bir[ni] = bi[ce + ni]; biz[ni] = bi[128 + ce + ni]; bin_[ni] = bi[256 + ce + ni];
        bhr[ni] = bh[ce + ni]; bhz[ni] = bh[128 + ce + ni]; bhn[ni] = bh[256 + ce + ni];
    }
    const uint* Xin_u = (const uint*)Xin;
    uint* Xout_u = (uint*)Xout;
    const int cpair = (c0 >> 1) + l15;
    #pragma unroll
    for (int mi = 0; mi < 4; ++mi)
        #pragma unroll
        for (int reg = 0; reg < 4; ++reg) {
            size_t r = row0 + mi * 16 + quad * 4 + reg;
            uint xo = Xin_u[r * 64 + cpair];
            float xold[2] = { bflo(xo), bfhi(xo) };
            float res[2];
            #pragma unroll
            for (int ni = 0; ni < 2; ++ni) {
                float rs = accR[mi][ni][reg] + bir[ni] + bhr[ni];
                float zs = accZ[mi][ni][reg] + biz[ni] + bhz[ni];
                float rr = 1.f / (1.f + __expf(-rs));
                float zz = 1.f / (1.f + __expf(-zs));
                float nn = tanhf(accI[mi][ni][reg] + bin_[ni] + rr * (accHN[mi][ni][reg] + bhn[ni]));
                res[ni] = (1.f - zz) * nn + zz * xold[ni];
            }
            Xout_u[r * 64 + cpair] = packbf(res[0], res[1]);
        }
}

// ---------------------------------------------------------------------------
// Launch.  Workspace (bytes):
//   XA  bf16 NTOT*128  @ 0            (35,651,584)
//   XB  bf16 NTOT*128  @ 35,651,584   (35,651,584)  [later hm2 33.5M]
//   P   bf16 NTOT*128  @ 71,303,168   (35,651,584)  [later hm1 33.5M, then msgs 16.8M]
//   Wb  bf16 196608    @ 106,954,752  (393,216)
//   WCI bf16 2*384*128 @ 107,347,968  (196,608)
//   NM  f32 8192*64    @ 107,544,576  (2,097,152)
//   HR1 bf16 8192*128  @ 109,641,728  (2,097,152)
//   HR2 bf16 8192*128  @ 111,738,880  (2,097,152)
//   CSR ints           @ 113,836,032  (196,608)
//   L1  int 262144     @ 114,032,640  (1,048,576)
//   L2  int 131072     @ 115,081,216  (524,288)
//   total 115,605,504 B
// ---------------------------------------------------------------------------
extern "C" void kernel_launch(void* const* d_in, const int* in_sizes, int n_in,
                              void* d_out, int out_size, void* d_ws, size_t ws_size,
                              hipStream_t stream) {
    (void)in_sizes; (void)n_in; (void)out_size;
    const float* jvals  = (const float*)d_in[0];
    const int*   row    = (const int*)d_in[2];
    const int*   col    = (const int*)d_in[3];
    const float* conv_W = (const float*)d_in[4];
    const float* gru_wi = (const float*)d_in[5];
    const float* gru_wh = (const float*)d_in[6];
    const float* gru_bi = (const float*)d_in[7];
    const float* gru_bh = (const float*)d_in[8];
    const float* mp_W1  = (const float*)d_in[9];
    const float* mp_b1  = (const float*)d_in[10];
    const float* mp_W2  = (const float*)d_in[11];
    const float* mp_b2  = (const float*)d_in[12];
    const float* mp_W3  = (const float*)d_in[13];
    const float* mp_b3  = (const float*)d_in[14];
    const float* ro_b1  = (const float*)d_in[16];
    const float* ro_b2  = (const float*)d_in[18];
    const float* ro_W3  = (const float*)d_in[19];
    const float* ro_b3  = (const float*)d_in[20];

    constexpr size_t OFF_XB  = 35651584ull;
    constexpr size_t OFF_P   = 71303168ull;
    constexpr size_t OFF_W   = 106954752ull;
    constexpr size_t OFF_WCI = 107347968ull;
    constexpr size_t OFF_NM  = 107544576ull;
    constexpr size_t OFF_HR1 = 109641728ull;
    constexpr size_t OFF_HR2 = 111738880ull;
    constexpr size_t OFF_CSR = 113836032ull;
    constexpr size_t OFF_L1  = 114032640ull;
    constexpr size_t OFF_L2  = 115081216ull;
    constexpr size_t WS_NEED = 115605504ull;
    if (ws_size < WS_NEED) return;

    char* ws = (char*)d_ws;
    ushort* Xa   = (ushort*)ws;
    ushort* Xb2  = (ushort*)(ws + OFF_XB);
    ushort* P    = (ushort*)(ws + OFF_P);
    ushort* hm1  = (ushort*)(ws + OFF_P);     // after GRU layers
    ushort* hm2  = (ushort*)(ws + OFF_XB);    // after layer-2 GRU
    ushort* msgs = (ushort*)(ws + OFF_P);     // after MLP2 (overwrites hm1)
    ushort* Wb   = (ushort*)(ws + OFF_W);
    ushort* Wci  = (ushort*)(ws + OFF_WCI);
    float*  nm   = (float*)(ws + OFF_NM);
    ushort* hr1  = (ushort*)(ws + OFF_HR1);
    ushort* hr2  = (ushort*)(ws + OFF_HR2);
    int* deg    = (int*)(ws + OFF_CSR);
    int* start  = deg + 8192;
    int* cur    = deg + 16384;
    int* deg2   = deg + 24576;
    int* start2 = deg + 32768;
    int* cur2   = deg + 40960;
    int* list   = (int*)(ws + OFF_L1);
    int* list2  = (int*)(ws + OFF_L2);

    dim3 blk(256);

    k_convert_weights<<<768, blk, 0, stream>>>(conv_W, gru_wi, gru_wh, mp_W1, mp_W2, mp_W3,
                                               (const float*)d_in[15], (const float*)d_in[17], Wb);
    k_make_wci<<<384, blk, 0, stream>>>(conv_W, gru_wi, Wci);
    k_init_x<<<NTOT * H / 256, blk, 0, stream>>>(Xa, jvals);
    k_zero_deg<<<32, blk, 0, stream>>>(deg, deg2);
    k_deg_count<<<N_EDGES / 256, blk, 0, stream>>>(row, col, deg, deg2);
    k_scan<<<1, blk, 0, stream>>>(deg, start, cur, deg2, start2, cur2);
    k_fill<<<N_EDGES / 256, blk, 0, stream>>>(row, col, cur, cur2, list, list2);

    ushort* Xcur = Xa;
    ushort* Xnxt = Xb2;
    for (int l = 0; l < 2; ++l) {
        k_agg_factors<<<N_EDGES * 64 / 256, blk, 0, stream>>>((uint*)P, (const uint*)Xcur, row, col);
        k_agg_nodes<<<N_NODES / 4, blk, 0, stream>>>((uint*)P, (const uint*)Xcur, start, deg, list);
        k_gru3<<<dim3(4, NTOT / 256), blk, 0, stream>>>(P, Xcur, Xnxt,
            Wci + (size_t)l * 49152, Wb + 81920, gru_bi, gru_bh);
        ushort* t = Xcur; Xcur = Xnxt; Xnxt = t;
    }
    // Xcur == Xa after 2 layers

    // edge MLP on factor rows
    k_gemm2<128, false, true, false><<<N_EDGES / 128, blk, 0, stream>>>(
        Xcur + (size_t)N_NODES * H, Wb + 131072, mp_b1, hm1, 128, 128);
    k_gemm2<128, false, true, false><<<N_EDGES / 128, blk, 0, stream>>>(
        hm1, Wb + 147456, mp_b2, hm2, 128, 128);
    k_gemm2<64, false, false, false><<<N_EDGES / 128, blk, 0, stream>>>(
        hm2, Wb + 163840, mp_b3, msgs, 128, 128);

    // node_msgs = segment_sum(msgs, row)
    k_nm_gather<<<N_NODES / 4, blk, 0, stream>>>(nm, msgs, start2, deg2, list2);

    // readout
    k_gemm2<128, true, true, false><<<N_NODES / 128, blk, 0, stream>>>(
        nm, Wb + 172032, ro_b1, hr1, 64, 64);
    k_gemm2<128, false, true, false><<<N_NODES / 128, blk, 0, stream>>>(
        hr1, Wb + 180224, ro_b2, hr2, 128, 128);
    k_logits<<<N_NODES / 4, blk, 0, stream>>>(hr2, ro_W3, ro_b3, (float*)d_out);
}

// Round 5
// 454.401 us; speedup vs baseline: 1.6767x; 1.1098x over previous
//
#include <hip/hip_runtime.h>
#include <hip/hip_bf16.h>
#include <cstdint>

#define N_NODES 8192
#define N_EDGES 131072
#define NTOT 139264          // N_NODES + N_EDGES
#define H 128

typedef __attribute__((ext_vector_type(8))) short short8;
typedef __attribute__((ext_vector_type(4))) float floatx4;

__device__ __forceinline__ ushort f2bf(float f) {
    union { float f; uint32_t u; } v; v.f = f;
    uint32_t r = v.u + 0x7fffu + ((v.u >> 16) & 1u);   // RNE
    return (ushort)(r >> 16);
}
__device__ __forceinline__ float bf2f(ushort u) {
    union { uint32_t u; float f; } v; v.u = ((uint32_t)u) << 16;
    return v.f;
}
__device__ __forceinline__ float bflo(uint u) { union { uint32_t u; float f; } v; v.u = u << 16; return v.f; }
__device__ __forceinline__ float bfhi(uint u) { union { uint32_t u; float f; } v; v.u = u & 0xffff0000u; return v.f; }
__device__ __forceinline__ uint packbf(float a, float b) { return (uint)f2bf(a) | ((uint)f2bf(b) << 16); }

__device__ __forceinline__ short8 lds_load8(const ushort* p) {
    union { short8 s; uint2 u[2]; } r;
    r.u[0] = *(const uint2*)p;
    r.u[1] = *(const uint2*)(p + 4);
    return r.s;
}
__device__ __forceinline__ short8 glb_load8(const ushort* p) {
    union { short8 s; uint4 u; } r;
    r.u = *(const uint4*)p;
    return r.s;
}
__device__ __forceinline__ floatx4 mfma16(short8 a, short8 b, floatx4 c) {
    return __builtin_amdgcn_mfma_f32_16x16x32_bf16(a, b, c, 0, 0, 0);
}

// ---------------------------------------------------------------------------
// Weight pre-convert -> bf16 (N,K).  Elem offsets into Wb:
//   WI 32768 (region [0,32768) zeroed) | WH 81920 | M1 131072 | M2 147456 |
//   M3 163840 | R1 172032 | R2 180224 | end 196608
// ---------------------------------------------------------------------------
__global__ __launch_bounds__(256) void k_convert_weights(
    const float* __restrict__ convW, const float* __restrict__ wi, const float* __restrict__ wh,
    const float* __restrict__ m1, const float* __restrict__ m2, const float* __restrict__ m3,
    const float* __restrict__ r1, const float* __restrict__ r2, ushort* __restrict__ W)
{
    int idx = blockIdx.x * 256 + threadIdx.x;
    float v;
    if (idx < 32768) { W[idx] = 0; return; }
    else if (idx < 81920)  v = wi[idx - 32768];
    else if (idx < 131072) v = wh[idx - 81920];
    else if (idx < 147456) { int t = idx - 131072; int n = t >> 7, k = t & 127; v = m1[k * 128 + n]; }
    else if (idx < 163840) { int t = idx - 147456; int n = t >> 7, k = t & 127; v = m2[k * 128 + n]; }
    else if (idx < 172032) { int t = idx - 163840; int n = t >> 7, k = t & 127; v = m3[k * 64 + n];  }
    else if (idx < 180224) { int t = idx - 172032; int n = t >> 6, k = t & 63;  v = r1[k * 128 + n]; }
    else                   { int t = idx - 180224; int n = t >> 7, k = t & 127; v = r2[k * 128 + n]; }
    W[idx] = f2bf(v);
}

// Wci[l][n][k] = sum_j convW[l][k][j] * wi[n][j]   (N=384, K=128), bf16 out
__global__ __launch_bounds__(256) void k_make_wci(
    const float* __restrict__ convW, const float* __restrict__ wi, ushort* __restrict__ Wci)
{
    int idx = blockIdx.x * 256 + threadIdx.x;       // 2*384*128
    int l = idx / 49152, t = idx % 49152;
    int n = t >> 7, k = t & 127;
    const float* wc = convW + l * 16384 + k * 128;
    const float* wr = wi + n * 128;
    float s = 0.f;
    #pragma unroll 8
    for (int j = 0; j < 128; ++j) s = fmaf(wc[j], wr[j], s);
    Wci[idx] = f2bf(s);
}

// ---------------------------------------------------------------------------
// CSR build
// ---------------------------------------------------------------------------
__global__ __launch_bounds__(256) void k_zero_deg(int* __restrict__ deg, int* __restrict__ deg2) {
    int i = blockIdx.x * 256 + threadIdx.x;
    if (i < 8192) { deg[i] = 0; deg2[i] = 0; }
}

__global__ __launch_bounds__(256) void k_deg_count(const int* __restrict__ row, const int* __restrict__ col,
                                                   int* __restrict__ deg, int* __restrict__ deg2) {
    int e = blockIdx.x * 256 + threadIdx.x;
    atomicAdd(&deg[row[e]], 1);
    atomicAdd(&deg[col[e]], 1);
    atomicAdd(&deg2[row[e]], 1);
}

__global__ __launch_bounds__(256) void k_scan(const int* __restrict__ deg, int* __restrict__ start, int* __restrict__ cur,
                                              const int* __restrict__ deg2, int* __restrict__ start2, int* __restrict__ cur2) {
    __shared__ int s1[256], s2[256];
    int tid = threadIdx.x, base = tid * 32;
    int a = 0, b = 0;
    for (int i = 0; i < 32; ++i) { a += deg[base + i]; b += deg2[base + i]; }
    s1[tid] = a; s2[tid] = b;
    __syncthreads();
    if (tid == 0) {
        int acc = 0, acc2 = 0;
        for (int i = 0; i < 256; ++i) {
            int t = s1[i]; s1[i] = acc; acc += t;
            int u = s2[i]; s2[i] = acc2; acc2 += u;
        }
    }
    __syncthreads();
    int off = s1[tid], off2 = s2[tid];
    for (int i = 0; i < 32; ++i) {
        start[base + i] = off;  cur[base + i] = off;   off += deg[base + i];
        start2[base + i] = off2; cur2[base + i] = off2; off2 += deg2[base + i];
    }
}

__global__ __launch_bounds__(256) void k_fill(const int* __restrict__ row, const int* __restrict__ col,
                                              int* __restrict__ cur, int* __restrict__ cur2,
                                              int* __restrict__ list, int* __restrict__ list2) {
    int e = blockIdx.x * 256 + threadIdx.x;
    int p = atomicAdd(&cur[row[e]], 1);  list[p] = e;
    int q = atomicAdd(&cur[col[e]], 1);  list[q] = e;
    int r2 = atomicAdd(&cur2[row[e]], 1); list2[r2] = e;
}

// ---------------------------------------------------------------------------
// Elementwise / gather
// ---------------------------------------------------------------------------
__global__ __launch_bounds__(256) void k_init_x(ushort* __restrict__ X, const float* __restrict__ jvals) {
    int idx = blockIdx.x * 256 + threadIdx.x;
    int i = idx >> 7, c = idx & 127;
    float v = 0.f;
    if (i >= N_NODES) {
        int e = i - N_NODES;
        if (c == 0) v = 1.f;
        else if (c == 1) v = jvals[e];
    }
    X[idx] = f2bf(v);
}

__global__ __launch_bounds__(256) void k_agg_factors(uint* __restrict__ P, const uint* __restrict__ X,
                                                     const int* __restrict__ row, const int* __restrict__ col) {
    int idx = blockIdx.x * 256 + threadIdx.x;
    int e = idx >> 6, l = idx & 63;
    uint a = X[(size_t)row[e] * 64 + l];
    uint b = X[(size_t)col[e] * 64 + l];
    P[(size_t)(N_NODES + e) * 64 + l] = packbf(bflo(a) + bflo(b), bfhi(a) + bfhi(b));
}

__global__ __launch_bounds__(256) void k_agg_nodes(uint* __restrict__ P, const uint* __restrict__ X,
                                                   const int* __restrict__ start, const int* __restrict__ deg,
                                                   const int* __restrict__ list) {
    int node = blockIdx.x * 4 + (threadIdx.x >> 6);
    int lane = threadIdx.x & 63;
    int s = start[node], d = deg[node];
    float a0 = 0.f, b0 = 0.f, a1 = 0.f, b1 = 0.f;
    int i = 0;
    for (; i + 1 < d; i += 2) {
        uint v0 = X[(size_t)(N_NODES + list[s + i]) * 64 + lane];
        uint v1 = X[(size_t)(N_NODES + list[s + i + 1]) * 64 + lane];
        a0 += bflo(v0); b0 += bfhi(v0);
        a1 += bflo(v1); b1 += bfhi(v1);
    }
    if (i < d) {
        uint v0 = X[(size_t)(N_NODES + list[s + i]) * 64 + lane];
        a0 += bflo(v0); b0 += bfhi(v0);
    }
    P[(size_t)node * 64 + lane] = packbf(a0 + a1, b0 + b1);
}

// node_msgs = segment_sum(msgs, row) via row-CSR; msgs bf16
__global__ __launch_bounds__(256) void k_nm_gather(float* __restrict__ nm, const ushort* __restrict__ msgs,
                                                   const int* __restrict__ start2, const int* __restrict__ deg2,
                                                   const int* __restrict__ list2) {
    int node = blockIdx.x * 4 + (threadIdx.x >> 6);
    int lane = threadIdx.x & 63;
    int s = start2[node], d = deg2[node];
    float a0 = 0.f, a1 = 0.f;
    int i = 0;
    for (; i + 1 < d; i += 2) {
        a0 += bf2f(msgs[(size_t)list2[s + i] * 64 + lane]);
        a1 += bf2f(msgs[(size_t)list2[s + i + 1] * 64 + lane]);
    }
    if (i < d) a0 += bf2f(msgs[(size_t)list2[s + i] * 64 + lane]);
    nm[(size_t)node * 64 + lane] = a0 + a1;
}

__global__ __launch_bounds__(256) void k_logits(const ushort* __restrict__ hr2, const float* __restrict__ W3,
                                                const float* __restrict__ b3, float* __restrict__ out) {
    int r = blockIdx.x * 4 + (threadIdx.x >> 6);
    int lane = threadIdx.x & 63;
    float l0 = 0.f, l1 = 0.f;
    for (int k = lane; k < H; k += 64) {
        float hv = bf2f(hr2[(size_t)r * H + k]);
        l0 = fmaf(hv, W3[k * 2 + 0], l0);
        l1 = fmaf(hv, W3[k * 2 + 1], l1);
    }
    for (int off = 32; off; off >>= 1) { l0 += __shfl_down(l0, off); l1 += __shfl_down(l1, off); }
    if (lane == 0) {
        l0 += b3[0]; l1 += b3[1];
        float mx = fmaxf(l0, l1);
        float e0 = __expf(l0 - mx), e1 = __expf(l1 - mx), s = e0 + e1;
        out[r * 2 + 0] = e0 / s;
        out[r * 2 + 1] = e1 / s;
    }
}

// ---------------------------------------------------------------------------
// MFMA GEMM v2 (readout): single-barrier full-tile staging. BN=128 only here.
// ---------------------------------------------------------------------------
template<int BN, bool AF32, bool RELU, bool OUTF32>
__global__ __launch_bounds__(256) void k_gemm2(
    const void* __restrict__ Aptr, const ushort* __restrict__ Bt,
    const float* __restrict__ bias, void* __restrict__ Cptr, int K, int lda)
{
    constexpr int BM = 128, LK = 136;
    constexpr int MI = (BN == 128) ? 4 : 2;
    constexpr int NI = 4;
    __shared__ ushort As[BM * LK];
    __shared__ ushort Bs[BN * LK];
    const int tid = threadIdx.x;
    const size_t row0 = (size_t)blockIdx.x * BM;
    const int kpc = K >> 3;

    if (AF32) {
        const float* A = (const float*)Aptr;
        for (int id = tid; id < BM * kpc; id += 256) {
            int m = id / kpc, kc = id - m * kpc;
            float4 v0 = *(const float4*)(A + (row0 + m) * lda + kc * 8);
            float4 v1 = *(const float4*)(A + (row0 + m) * lda + kc * 8 + 4);
            uint4 u;
            u.x = packbf(v0.x, v0.y); u.y = packbf(v0.z, v0.w);
            u.z = packbf(v1.x, v1.y); u.w = packbf(v1.z, v1.w);
            *(uint4*)&As[m * LK + kc * 8] = u;
        }
    } else {
        const ushort* A = (const ushort*)Aptr;
        for (int id = tid; id < BM * kpc; id += 256) {
            int m = id / kpc, kc = id - m * kpc;
            *(uint4*)&As[m * LK + kc * 8] = *(const uint4*)(A + (row0 + m) * (size_t)lda + kc * 8);
        }
    }
    for (int id = tid; id < BN * kpc; id += 256) {
        int slot = id / kpc, kc = id - slot * kpc;
        int gcol = (slot & ~63) + 4 * (slot & 15) + ((slot >> 4) & 3);
        *(uint4*)&Bs[slot * LK + kc * 8] = *(const uint4*)(Bt + (size_t)gcol * K + kc * 8);
    }
    __syncthreads();

    const int w = tid >> 6, lane = tid & 63, quad = lane >> 4, l15 = lane & 15;
    const int wr = (BN == 128) ? (w >> 1) * 64 : w * 32;
    const int wc = (BN == 128) ? (w & 1) * 64 : 0;

    floatx4 acc[MI][NI];
    #pragma unroll
    for (int i = 0; i < MI; ++i)
        #pragma unroll
        for (int j = 0; j < NI; ++j) acc[i][j] = (floatx4)0.f;

    for (int k0 = 0; k0 < K; k0 += 32) {
        short8 a[MI], b[NI];
        #pragma unroll
        for (int mi = 0; mi < MI; ++mi) a[mi] = lds_load8(&As[(wr + mi * 16 + l15) * LK + k0 + quad * 8]);
        #pragma unroll
        for (int ni = 0; ni < NI; ++ni) b[ni] = lds_load8(&Bs[(wc + ni * 16 + l15) * LK + k0 + quad * 8]);
        #pragma unroll
        for (int mi = 0; mi < MI; ++mi)
            #pragma unroll
            for (int ni = 0; ni < NI; ++ni)
                acc[mi][ni] = mfma16(a[mi], b[ni], acc[mi][ni]);
    }

    float bv[NI];
    #pragma unroll
    for (int ni = 0; ni < NI; ++ni) bv[ni] = bias ? bias[wc + 4 * l15 + ni] : 0.f;
    #pragma unroll
    for (int mi = 0; mi < MI; ++mi) {
        #pragma unroll
        for (int reg = 0; reg < 4; ++reg) {
            size_t r = row0 + wr + mi * 16 + quad * 4 + reg;
            float v[NI];
            #pragma unroll
            for (int ni = 0; ni < NI; ++ni) {
                v[ni] = acc[mi][ni][reg] + bv[ni];
                if (RELU) v[ni] = fmaxf(v[ni], 0.f);
            }
            if (OUTF32) {
                float4 o = make_float4(v[0], v[1], v[2], v[3]);
                *(float4*)((float*)Cptr + r * BN + wc + 4 * l15) = o;
            } else {
                uint2 o = make_uint2(packbf(v[0], v[1]), packbf(v[2], v[3]));
                *(uint2*)((ushort*)Cptr + r * BN + wc + 4 * l15) = o;
            }
        }
    }
}

// ---------------------------------------------------------------------------
// Fused GRU v4: grid (4 col-groups, NTOT/128).  Two-phase weight staging into
// ONE 26 KB LDS buffer (WCI phase 0, WH phase 1) -> 3 blocks/CU occupancy.
// Waves: 32 rows each (MI=2); A-frags straight from global (L2/L3-hot).
// Column-permuted slots: slot ni*16+j <-> col c0 + 2*j + ni.
// ---------------------------------------------------------------------------
__global__ __launch_bounds__(256, 3) void k_gru4(
    const ushort* __restrict__ P, const ushort* __restrict__ Xin, ushort* __restrict__ Xout,
    const ushort* __restrict__ WCI, const ushort* __restrict__ WH,
    const float* __restrict__ bi, const float* __restrict__ bh)
{
    constexpr int LK = 136;
    __shared__ ushort Ws[3 * 32 * LK];     // 26112 B
    const int tid = threadIdx.x;
    const int c0 = blockIdx.x * 32;
    const size_t brow0 = (size_t)blockIdx.y * 128;
    const int w = tid >> 6, lane = tid & 63, quad = lane >> 4, l15 = lane & 15;
    const size_t row0 = brow0 + w * 32;

    floatx4 accR[2][2], accZ[2][2], accI[2][2], accHN[2][2];
    #pragma unroll
    for (int i = 0; i < 2; ++i)
        #pragma unroll
        for (int j = 0; j < 2; ++j) {
            accR[i][j] = (floatx4)0.f; accZ[i][j] = (floatx4)0.f;
            accI[i][j] = (floatx4)0.f; accHN[i][j] = (floatx4)0.f;
        }

    #pragma unroll
    for (int h = 0; h < 2; ++h) {
        if (h) __syncthreads();                       // phase-0 readers done
        const ushort* Wsrc = h ? WH : WCI;
        for (int id = tid; id < 1536; id += 256) {    // 3*32*16 uint4
            int kc = id & 15, slot = (id >> 4) & 31, s = id >> 9;
            int gcol = c0 + 2 * (slot & 15) + (slot >> 4);
            *(uint4*)&Ws[(s * 32 + slot) * LK + kc * 8] =
                *(const uint4*)(Wsrc + (size_t)(s * 128 + gcol) * 128 + kc * 8);
        }
        __syncthreads();
        const ushort* Ah = h ? Xin : P;
        #pragma unroll
        for (int k4 = 0; k4 < 4; ++k4) {
            const int k0 = k4 * 32;
            short8 a[2];
            #pragma unroll
            for (int mi = 0; mi < 2; ++mi)
                a[mi] = glb_load8(Ah + (row0 + mi * 16 + l15) * H + k0 + quad * 8);
            #pragma unroll
            for (int s = 0; s < 3; ++s) {
                short8 b[2];
                #pragma unroll
                for (int ni = 0; ni < 2; ++ni)
                    b[ni] = lds_load8(&Ws[(s * 32 + ni * 16 + l15) * LK + k0 + quad * 8]);
                #pragma unroll
                for (int mi = 0; mi < 2; ++mi)
                    #pragma unroll
                    for (int ni = 0; ni < 2; ++ni) {
                        if (s == 0)      accR[mi][ni] = mfma16(a[mi], b[ni], accR[mi][ni]);
                        else if (s == 1) accZ[mi][ni] = mfma16(a[mi], b[ni], accZ[mi][ni]);
                        else if (h == 0) accI[mi][ni] = mfma16(a[mi], b[ni], accI[mi][ni]);
                        else             accHN[mi][ni] = mfma16(a[mi], b[ni], accHN[mi][ni]);
                    }
            }
        }
    }

    // epilogue: lane holds cols (c0+2*l15, c0+2*l15+1)
    const int ce = c0 + 2 * l15;
    float bir[2], biz[2], bin_[2], bhr[2], bhz[2], bhn[2];
    #pragma unroll
    for (int ni = 0; ni < 2; ++ni) {
        bir[ni] = bi[ce + ni]; biz[ni] = bi[128 + ce + ni]; bin_[ni] = bi[256 + ce + ni];
        bhr[ni] = bh[ce + ni]; bhz[ni] = bh[128 + ce + ni]; bhn[ni] = bh[256 + ce + ni];
    }
    const uint* Xin_u = (const uint*)Xin;
    uint* Xout_u = (uint*)Xout;
    const int cpair = (c0 >> 1) + l15;
    #pragma unroll
    for (int mi = 0; mi < 2; ++mi)
        #pragma unroll
        for (int reg = 0; reg < 4; ++reg) {
            size_t r = row0 + mi * 16 + quad * 4 + reg;
            uint xo = Xin_u[r * 64 + cpair];
            float xold[2] = { bflo(xo), bfhi(xo) };
            float res[2];
            #pragma unroll
            for (int ni = 0; ni < 2; ++ni) {
                float rs = accR[mi][ni][reg] + bir[ni] + bhr[ni];
                float zs = accZ[mi][ni][reg] + biz[ni] + bhz[ni];
                float rr = 1.f / (1.f + __expf(-rs));
                float zz = 1.f / (1.f + __expf(-zs));
                float nn = tanhf(accI[mi][ni][reg] + bin_[ni] + rr * (accHN[mi][ni][reg] + bhn[ni]));
                res[ni] = (1.f - zz) * nn + zz * xold[ni];
            }
            Xout_u[r * 64 + cpair] = packbf(res[0], res[1]);
        }
}

// ---------------------------------------------------------------------------
// Fused edge-MLP: per block 128 factor rows; A-tile staged once in LDS (T),
// weights streamed per-64-col group (Wv); C written back into T between
// stages.  hm1/hm2 never touch HBM.  LDS = 33792 + 16896 = 50688 B.
// ---------------------------------------------------------------------------
__global__ __launch_bounds__(256, 3) void k_mlp(
    const ushort* __restrict__ Xf, const ushort* __restrict__ W1, const ushort* __restrict__ W2,
    const ushort* __restrict__ W3, const float* __restrict__ b1, const float* __restrict__ b2,
    const float* __restrict__ b3, ushort* __restrict__ msgs)
{
    constexpr int LK = 132;
    __shared__ ushort T[128 * LK];       // 33792 B
    __shared__ ushort Wv[64 * LK];       // 16896 B
    const int tid = threadIdx.x;
    const size_t row0 = (size_t)blockIdx.x * 128;
    const int w = tid >> 6, lane = tid & 63, quad = lane >> 4, l15 = lane & 15;
    const int wr = w * 32;

    for (int id = tid; id < 2048; id += 256) {   // A tile: 128 rows x 16 uint4
        int m = id >> 4, kc = (id & 15) * 8;
        *(uint4*)&T[m * LK + kc] = *(const uint4*)(Xf + (row0 + m) * H + kc);
    }

    #pragma unroll
    for (int stage = 0; stage < 3; ++stage) {
        const ushort* Wsrc = (stage == 0) ? W1 : (stage == 1) ? W2 : W3;
        const float* bias = (stage == 0) ? b1 : (stage == 1) ? b2 : b3;
        const int NCG = (stage == 2) ? 1 : 2;    // 64-col groups
        floatx4 acc[2][2][4];
        #pragma unroll
        for (int c = 0; c < 2; ++c)
            #pragma unroll
            for (int i = 0; i < 2; ++i)
                #pragma unroll
                for (int j = 0; j < 4; ++j) acc[c][i][j] = (floatx4)0.f;

        for (int cg = 0; cg < NCG; ++cg) {
            __syncthreads();                     // prior T/Wv readers done
            for (int id = tid; id < 1024; id += 256) {   // 64 slots x 16 uint4
                int slot = id >> 4, kc = (id & 15) * 8;
                int gcol = cg * 64 + 4 * (slot & 15) + (slot >> 4);
                *(uint4*)&Wv[slot * LK + kc] = *(const uint4*)(Wsrc + (size_t)gcol * 128 + kc);
            }
            __syncthreads();
            for (int k0 = 0; k0 < 128; k0 += 32) {
                short8 a[2], b[4];
                #pragma unroll
                for (int mi = 0; mi < 2; ++mi)
                    a[mi] = lds_load8(&T[(wr + mi * 16 + l15) * LK + k0 + quad * 8]);
                #pragma unroll
                for (int ni = 0; ni < 4; ++ni)
                    b[ni] = lds_load8(&Wv[(ni * 16 + l15) * LK + k0 + quad * 8]);
                #pragma unroll
                for (int mi = 0; mi < 2; ++mi)
                    #pragma unroll
                    for (int ni = 0; ni < 4; ++ni)
                        acc[cg][mi][ni] = mfma16(a[mi], b[ni], acc[cg][mi][ni]);
            }
        }
        __syncthreads();                         // all T reads done before rewrite

        if (stage < 2) {
            #pragma unroll
            for (int cg = 0; cg < 2; ++cg) {
                float bv[4];
                #pragma unroll
                for (int ni = 0; ni < 4; ++ni) bv[ni] = bias[cg * 64 + 4 * l15 + ni];
                #pragma unroll
                for (int mi = 0; mi < 2; ++mi)
                    #pragma unroll
                    for (int reg = 0; reg < 4; ++reg) {
                        int r = wr + mi * 16 + quad * 4 + reg;
                        float v[4];
                        #pragma unroll
                        for (int ni = 0; ni < 4; ++ni)
                            v[ni] = fmaxf(acc[cg][mi][ni][reg] + bv[ni], 0.f);
                        uint2 o = make_uint2(packbf(v[0], v[1]), packbf(v[2], v[3]));
                        *(uint2*)&T[r * LK + cg * 64 + 4 * l15] = o;
                    }
            }
            __syncthreads();                     // T rewrite visible
        } else {
            float bv[4];
            #pragma unroll
            for (int ni = 0; ni < 4; ++ni) bv[ni] = bias[4 * l15 + ni];
            #pragma unroll
            for (int mi = 0; mi < 2; ++mi)
                #pragma unroll
                for (int reg = 0; reg < 4; ++reg) {
                    size_t r = row0 + wr + mi * 16 + quad * 4 + reg;
                    float v[4];
                    #pragma unroll
                    for (int ni = 0; ni < 4; ++ni) v[ni] = acc[0][mi][ni][reg] + bv[ni];
                    uint2 o = make_uint2(packbf(v[0], v[1]), packbf(v[2], v[3]));
                    *(uint2*)(msgs + r * 64 + 4 * l15) = o;
                }
        }
    }
}

// ---------------------------------------------------------------------------
// Launch.  Workspace layout identical to R4 (115,605,504 B); hm1/hm2 regions
// now unused (MLP fused); msgs (bf16) lives at OFF_P.
// ---------------------------------------------------------------------------
extern "C" void kernel_launch(void* const* d_in, const int* in_sizes, int n_in,
                              void* d_out, int out_size, void* d_ws, size_t ws_size,
                              hipStream_t stream) {
    (void)in_sizes; (void)n_in; (void)out_size;
    const float* jvals  = (const float*)d_in[0];
    const int*   row    = (const int*)d_in[2];
    const int*   col    = (const int*)d_in[3];
    const float* conv_W = (const float*)d_in[4];
    const float* gru_wi = (const float*)d_in[5];
    const float* gru_wh = (const float*)d_in[6];
    const float* gru_bi = (const float*)d_in[7];
    const float* gru_bh = (const float*)d_in[8];
    const float* mp_W1  = (const float*)d_in[9];
    const float* mp_b1  = (const float*)d_in[10];
    const float* mp_W2  = (const float*)d_in[11];
    const float* mp_b2  = (const float*)d_in[12];
    const float* mp_W3  = (const float*)d_in[13];
    const float* mp_b3  = (const float*)d_in[14];
    const float* ro_b1  = (const float*)d_in[16];
    const float* ro_b2  = (const float*)d_in[18];
    const float* ro_W3  = (const float*)d_in[19];
    const float* ro_b3  = (const float*)d_in[20];

    constexpr size_t OFF_XB  = 35651584ull;
    constexpr size_t OFF_P   = 71303168ull;
    constexpr size_t OFF_W   = 106954752ull;
    constexpr size_t OFF_WCI = 107347968ull;
    constexpr size_t OFF_NM  = 107544576ull;
    constexpr size_t OFF_HR1 = 109641728ull;
    constexpr size_t OFF_HR2 = 111738880ull;
    constexpr size_t OFF_CSR = 113836032ull;
    constexpr size_t OFF_L1  = 114032640ull;
    constexpr size_t OFF_L2  = 115081216ull;
    constexpr size_t WS_NEED = 115605504ull;
    if (ws_size < WS_NEED) return;

    char* ws = (char*)d_ws;
    ushort* Xa   = (ushort*)ws;
    ushort* Xb2  = (ushort*)(ws + OFF_XB);
    ushort* P    = (ushort*)(ws + OFF_P);
    ushort* msgs = (ushort*)(ws + OFF_P);     // after GRU layers (P dead)
    ushort* Wb   = (ushort*)(ws + OFF_W);
    ushort* Wci  = (ushort*)(ws + OFF_WCI);
    float*  nm   = (float*)(ws + OFF_NM);
    ushort* hr1  = (ushort*)(ws + OFF_HR1);
    ushort* hr2  = (ushort*)(ws + OFF_HR2);
    int* deg    = (int*)(ws + OFF_CSR);
    int* start  = deg + 8192;
    int* cur    = deg + 16384;
    int* deg2   = deg + 24576;
    int* start2 = deg + 32768;
    int* cur2   = deg + 40960;
    int* list   = (int*)(ws + OFF_L1);
    int* list2  = (int*)(ws + OFF_L2);

    dim3 blk(256);

    k_convert_weights<<<768, blk, 0, stream>>>(conv_W, gru_wi, gru_wh, mp_W1, mp_W2, mp_W3,
                                               (const float*)d_in[15], (const float*)d_in[17], Wb);
    k_make_wci<<<384, blk, 0, stream>>>(conv_W, gru_wi, Wci);
    k_init_x<<<NTOT * H / 256, blk, 0, stream>>>(Xa, jvals);
    k_zero_deg<<<32, blk, 0, stream>>>(deg, deg2);
    k_deg_count<<<N_EDGES / 256, blk, 0, stream>>>(row, col, deg, deg2);
    k_scan<<<1, blk, 0, stream>>>(deg, start, cur, deg2, start2, cur2);
    k_fill<<<N_EDGES / 256, blk, 0, stream>>>(row, col, cur, cur2, list, list2);

    ushort* Xcur = Xa;
    ushort* Xnxt = Xb2;
    for (int l = 0; l < 2; ++l) {
        k_agg_factors<<<N_EDGES * 64 / 256, blk, 0, stream>>>((uint*)P, (const uint*)Xcur, row, col);
        k_agg_nodes<<<N_NODES / 4, blk, 0, stream>>>((uint*)P, (const uint*)Xcur, start, deg, list);
        k_gru4<<<dim3(4, NTOT / 128), blk, 0, stream>>>(P, Xcur, Xnxt,
            Wci + (size_t)l * 49152, Wb + 81920, gru_bi, gru_bh);
        ushort* t = Xcur; Xcur = Xnxt; Xnxt = t;
    }
    // Xcur == Xa after 2 layers

    // fused edge MLP -> msgs (bf16)
    k_mlp<<<N_EDGES / 128, blk, 0, stream>>>(
        Xcur + (size_t)N_NODES * H, Wb + 131072, Wb + 147456, Wb + 163840,
        mp_b1, mp_b2, mp_b3, msgs);

    // node_msgs = segment_sum(msgs, row)
    k_nm_gather<<<N_NODES / 4, blk, 0, stream>>>(nm, msgs, start2, deg2, list2);

    // readout
    k_gemm2<128, true, true, false><<<N_NODES / 128, blk, 0, stream>>>(
        nm, Wb + 172032, ro_b1, hr1, 64, 64);
    k_gemm2<128, false, true, false><<<N_NODES / 128, blk, 0, stream>>>(
        hr1, Wb + 180224, ro_b2, hr2, 128, 128);
    k_logits<<<N_NODES / 4, blk, 0, stream>>>(hr2, ro_W3, ro_b3, (float*)d_out);
}

// Round 6
// 434.649 us; speedup vs baseline: 1.7529x; 1.0454x over previous
//
#include <hip/hip_runtime.h>
#include <hip/hip_bf16.h>
#include <cstdint>

#define N_NODES 8192
#define N_EDGES 131072
#define NTOT 139264          // N_NODES + N_EDGES
#define H 128

typedef __attribute__((ext_vector_type(8))) short short8;
typedef __attribute__((ext_vector_type(4))) float floatx4;

__device__ __forceinline__ ushort f2bf(float f) {
    union { float f; uint32_t u; } v; v.f = f;
    uint32_t r = v.u + 0x7fffu + ((v.u >> 16) & 1u);   // RNE
    return (ushort)(r >> 16);
}
__device__ __forceinline__ float bf2f(ushort u) {
    union { uint32_t u; float f; } v; v.u = ((uint32_t)u) << 16;
    return v.f;
}
__device__ __forceinline__ float bflo(uint u) { union { uint32_t u; float f; } v; v.u = u << 16; return v.f; }
__device__ __forceinline__ float bfhi(uint u) { union { uint32_t u; float f; } v; v.u = u & 0xffff0000u; return v.f; }
__device__ __forceinline__ uint packbf(float a, float b) { return (uint)f2bf(a) | ((uint)f2bf(b) << 16); }

__device__ __forceinline__ float fsig(float x) {           // sigmoid: v_exp + v_rcp
    return __builtin_amdgcn_rcpf(1.f + __expf(-x));
}
__device__ __forceinline__ float ftanh(float x) {          // tanh = 2*sig(2x)-1
    return fmaf(2.f, fsig(2.f * x), -1.f);
}

__device__ __forceinline__ short8 lds_load8(const ushort* p) {
    union { short8 s; uint2 u[2]; } r;
    r.u[0] = *(const uint2*)p;
    r.u[1] = *(const uint2*)(p + 4);
    return r.s;
}
__device__ __forceinline__ short8 glb_load8(const ushort* p) {
    union { short8 s; uint4 u; } r;
    r.u = *(const uint4*)p;
    return r.s;
}
__device__ __forceinline__ floatx4 mfma16(short8 a, short8 b, floatx4 c) {
    return __builtin_amdgcn_mfma_f32_16x16x32_bf16(a, b, c, 0, 0, 0);
}

// ---------------------------------------------------------------------------
// Fused setup: weight convert (196608) + Wci compute (98304) + X init.
// Wb elem offsets: WI 32768 | WH 81920 | M1 131072 | M2 147456 | M3 163840 |
//   R1 172032 | R2 180224 | end 196608.  Wci: [l][n][k], 2*384*128.
// ---------------------------------------------------------------------------
__global__ __launch_bounds__(256) void k_setup(
    const float* __restrict__ convW, const float* __restrict__ wi, const float* __restrict__ wh,
    const float* __restrict__ m1, const float* __restrict__ m2, const float* __restrict__ m3,
    const float* __restrict__ r1, const float* __restrict__ r2,
    const float* __restrict__ jvals, ushort* __restrict__ W, ushort* __restrict__ Wci,
    ushort* __restrict__ X)
{
    int idx = blockIdx.x * 256 + threadIdx.x;
    if (idx < 196608) {
        float v;
        if (idx < 32768) { W[idx] = 0; return; }
        else if (idx < 81920)  v = wi[idx - 32768];
        else if (idx < 131072) v = wh[idx - 81920];
        else if (idx < 147456) { int t = idx - 131072; int n = t >> 7, k = t & 127; v = m1[k * 128 + n]; }
        else if (idx < 163840) { int t = idx - 147456; int n = t >> 7, k = t & 127; v = m2[k * 128 + n]; }
        else if (idx < 172032) { int t = idx - 163840; int n = t >> 7, k = t & 127; v = m3[k * 64 + n];  }
        else if (idx < 180224) { int t = idx - 172032; int n = t >> 6, k = t & 63;  v = r1[k * 128 + n]; }
        else                   { int t = idx - 180224; int n = t >> 7, k = t & 127; v = r2[k * 128 + n]; }
        W[idx] = f2bf(v);
    } else if (idx < 294912) {
        int t = idx - 196608;
        int l = t / 49152, tt = t % 49152;
        int n = tt >> 7, k = tt & 127;
        const float* wc = convW + l * 16384 + k * 128;
        const float* wr = wi + n * 128;
        float s = 0.f;
        #pragma unroll 8
        for (int j = 0; j < 128; ++j) s = fmaf(wc[j], wr[j], s);
        Wci[t] = f2bf(s);
    } else {
        int j = idx - 294912;                  // NTOT*H
        int i = j >> 7, c = j & 127;
        float v = 0.f;
        if (i >= N_NODES) {
            int e = i - N_NODES;
            if (c == 0) v = 1.f;
            else if (c == 1) v = jvals[e];
        }
        X[j] = f2bf(v);
    }
}

// ---------------------------------------------------------------------------
// CSR build
// ---------------------------------------------------------------------------
__global__ __launch_bounds__(256) void k_zero_deg(int* __restrict__ deg, int* __restrict__ deg2) {
    int i = blockIdx.x * 256 + threadIdx.x;
    if (i < 8192) { deg[i] = 0; deg2[i] = 0; }
}

__global__ __launch_bounds__(256) void k_deg_count(const int* __restrict__ row, const int* __restrict__ col,
                                                   int* __restrict__ deg, int* __restrict__ deg2) {
    int e = blockIdx.x * 256 + threadIdx.x;
    atomicAdd(&deg[row[e]], 1);
    atomicAdd(&deg[col[e]], 1);
    atomicAdd(&deg2[row[e]], 1);
}

__global__ __launch_bounds__(256) void k_scan(const int* __restrict__ deg, int* __restrict__ start, int* __restrict__ cur,
                                              const int* __restrict__ deg2, int* __restrict__ start2, int* __restrict__ cur2) {
    __shared__ int s1[256], s2[256];
    int tid = threadIdx.x, base = tid * 32;
    int a = 0, b = 0;
    for (int i = 0; i < 32; ++i) { a += deg[base + i]; b += deg2[base + i]; }
    s1[tid] = a; s2[tid] = b;
    __syncthreads();
    if (tid == 0) {
        int acc = 0, acc2 = 0;
        for (int i = 0; i < 256; ++i) {
            int t = s1[i]; s1[i] = acc; acc += t;
            int u = s2[i]; s2[i] = acc2; acc2 += u;
        }
    }
    __syncthreads();
    int off = s1[tid], off2 = s2[tid];
    for (int i = 0; i < 32; ++i) {
        start[base + i] = off;  cur[base + i] = off;   off += deg[base + i];
        start2[base + i] = off2; cur2[base + i] = off2; off2 += deg2[base + i];
    }
}

__global__ __launch_bounds__(256) void k_fill(const int* __restrict__ row, const int* __restrict__ col,
                                              int* __restrict__ cur, int* __restrict__ cur2,
                                              int* __restrict__ list, int* __restrict__ list2) {
    int e = blockIdx.x * 256 + threadIdx.x;
    int p = atomicAdd(&cur[row[e]], 1);  list[p] = e;
    int q = atomicAdd(&cur[col[e]], 1);  list[q] = e;
    int r2 = atomicAdd(&cur2[row[e]], 1); list2[r2] = e;
}

// ---------------------------------------------------------------------------
// Fused aggregation: blocks [0,32768) factor rows, [32768,34816) node rows.
// ---------------------------------------------------------------------------
__global__ __launch_bounds__(256) void k_agg(uint* __restrict__ P, const uint* __restrict__ X,
                                             const int* __restrict__ row, const int* __restrict__ col,
                                             const int* __restrict__ start, const int* __restrict__ deg,
                                             const int* __restrict__ list) {
    int b = blockIdx.x;
    if (b < 32768) {
        int idx = b * 256 + threadIdx.x;
        int e = idx >> 6, l = idx & 63;
        uint a = X[(size_t)row[e] * 64 + l];
        uint c = X[(size_t)col[e] * 64 + l];
        P[(size_t)(N_NODES + e) * 64 + l] = packbf(bflo(a) + bflo(c), bfhi(a) + bfhi(c));
    } else {
        int node = (b - 32768) * 4 + (threadIdx.x >> 6);
        int lane = threadIdx.x & 63;
        int s = start[node], d = deg[node];
        float a0 = 0.f, b0 = 0.f, a1 = 0.f, b1 = 0.f;
        int i = 0;
        for (; i + 1 < d; i += 2) {
            uint v0 = X[(size_t)(N_NODES + list[s + i]) * 64 + lane];
            uint v1 = X[(size_t)(N_NODES + list[s + i + 1]) * 64 + lane];
            a0 += bflo(v0); b0 += bfhi(v0);
            a1 += bflo(v1); b1 += bfhi(v1);
        }
        if (i < d) {
            uint v0 = X[(size_t)(N_NODES + list[s + i]) * 64 + lane];
            a0 += bflo(v0); b0 += bfhi(v0);
        }
        P[(size_t)node * 64 + lane] = packbf(a0 + a1, b0 + b1);
    }
}

// node_msgs = segment_sum(msgs, row) via row-CSR; msgs bf16
__global__ __launch_bounds__(256) void k_nm_gather(float* __restrict__ nm, const ushort* __restrict__ msgs,
                                                   const int* __restrict__ start2, const int* __restrict__ deg2,
                                                   const int* __restrict__ list2) {
    int node = blockIdx.x * 4 + (threadIdx.x >> 6);
    int lane = threadIdx.x & 63;
    int s = start2[node], d = deg2[node];
    float a0 = 0.f, a1 = 0.f;
    int i = 0;
    for (; i + 1 < d; i += 2) {
        a0 += bf2f(msgs[(size_t)list2[s + i] * 64 + lane]);
        a1 += bf2f(msgs[(size_t)list2[s + i + 1] * 64 + lane]);
    }
    if (i < d) a0 += bf2f(msgs[(size_t)list2[s + i] * 64 + lane]);
    nm[(size_t)node * 64 + lane] = a0 + a1;
}

__global__ __launch_bounds__(256) void k_logits(const ushort* __restrict__ hr2, const float* __restrict__ W3,
                                                const float* __restrict__ b3, float* __restrict__ out) {
    int r = blockIdx.x * 4 + (threadIdx.x >> 6);
    int lane = threadIdx.x & 63;
    float l0 = 0.f, l1 = 0.f;
    for (int k = lane; k < H; k += 64) {
        float hv = bf2f(hr2[(size_t)r * H + k]);
        l0 = fmaf(hv, W3[k * 2 + 0], l0);
        l1 = fmaf(hv, W3[k * 2 + 1], l1);
    }
    for (int off = 32; off; off >>= 1) { l0 += __shfl_down(l0, off); l1 += __shfl_down(l1, off); }
    if (lane == 0) {
        l0 += b3[0]; l1 += b3[1];
        float mx = fmaxf(l0, l1);
        float e0 = __expf(l0 - mx), e1 = __expf(l1 - mx), s = e0 + e1;
        out[r * 2 + 0] = e0 / s;
        out[r * 2 + 1] = e1 / s;
    }
}

// ---------------------------------------------------------------------------
// MFMA GEMM (readout): single-barrier full-tile staging.
// ---------------------------------------------------------------------------
template<int BN, bool AF32, bool RELU, bool OUTF32>
__global__ __launch_bounds__(256) void k_gemm2(
    const void* __restrict__ Aptr, const ushort* __restrict__ Bt,
    const float* __restrict__ bias, void* __restrict__ Cptr, int K, int lda)
{
    constexpr int BM = 128, LK = 136;
    constexpr int MI = (BN == 128) ? 4 : 2;
    constexpr int NI = 4;
    __shared__ ushort As[BM * LK];
    __shared__ ushort Bs[BN * LK];
    const int tid = threadIdx.x;
    const size_t row0 = (size_t)blockIdx.x * BM;
    const int kpc = K >> 3;

    if (AF32) {
        const float* A = (const float*)Aptr;
        for (int id = tid; id < BM * kpc; id += 256) {
            int m = id / kpc, kc = id - m * kpc;
            float4 v0 = *(const float4*)(A + (row0 + m) * lda + kc * 8);
            float4 v1 = *(const float4*)(A + (row0 + m) * lda + kc * 8 + 4);
            uint4 u;
            u.x = packbf(v0.x, v0.y); u.y = packbf(v0.z, v0.w);
            u.z = packbf(v1.x, v1.y); u.w = packbf(v1.z, v1.w);
            *(uint4*)&As[m * LK + kc * 8] = u;
        }
    } else {
        const ushort* A = (const ushort*)Aptr;
        for (int id = tid; id < BM * kpc; id += 256) {
            int m = id / kpc, kc = id - m * kpc;
            *(uint4*)&As[m * LK + kc * 8] = *(const uint4*)(A + (row0 + m) * (size_t)lda + kc * 8);
        }
    }
    for (int id = tid; id < BN * kpc; id += 256) {
        int slot = id / kpc, kc = id - slot * kpc;
        int gcol = (slot & ~63) + 4 * (slot & 15) + ((slot >> 4) & 3);
        *(uint4*)&Bs[slot * LK + kc * 8] = *(const uint4*)(Bt + (size_t)gcol * K + kc * 8);
    }
    __syncthreads();

    const int w = tid >> 6, lane = tid & 63, quad = lane >> 4, l15 = lane & 15;
    const int wr = (BN == 128) ? (w >> 1) * 64 : w * 32;
    const int wc = (BN == 128) ? (w & 1) * 64 : 0;

    floatx4 acc[MI][NI];
    #pragma unroll
    for (int i = 0; i < MI; ++i)
        #pragma unroll
        for (int j = 0; j < NI; ++j) acc[i][j] = (floatx4)0.f;

    for (int k0 = 0; k0 < K; k0 += 32) {
        short8 a[MI], b[NI];
        #pragma unroll
        for (int mi = 0; mi < MI; ++mi) a[mi] = lds_load8(&As[(wr + mi * 16 + l15) * LK + k0 + quad * 8]);
        #pragma unroll
        for (int ni = 0; ni < NI; ++ni) b[ni] = lds_load8(&Bs[(wc + ni * 16 + l15) * LK + k0 + quad * 8]);
        #pragma unroll
        for (int mi = 0; mi < MI; ++mi)
            #pragma unroll
            for (int ni = 0; ni < NI; ++ni)
                acc[mi][ni] = mfma16(a[mi], b[ni], acc[mi][ni]);
    }

    float bv[NI];
    #pragma unroll
    for (int ni = 0; ni < NI; ++ni) bv[ni] = bias ? bias[wc + 4 * l15 + ni] : 0.f;
    #pragma unroll
    for (int mi = 0; mi < MI; ++mi) {
        #pragma unroll
        for (int reg = 0; reg < 4; ++reg) {
            size_t r = row0 + wr + mi * 16 + quad * 4 + reg;
            float v[NI];
            #pragma unroll
            for (int ni = 0; ni < NI; ++ni) {
                v[ni] = acc[mi][ni][reg] + bv[ni];
                if (RELU) v[ni] = fmaxf(v[ni], 0.f);
            }
            if (OUTF32) {
                float4 o = make_float4(v[0], v[1], v[2], v[3]);
                *(float4*)((float*)Cptr + r * BN + wc + 4 * l15) = o;
            } else {
                uint2 o = make_uint2(packbf(v[0], v[1]), packbf(v[2], v[3]));
                *(uint2*)((ushort*)Cptr + r * BN + wc + 4 * l15) = o;
            }
        }
    }
}

// ---------------------------------------------------------------------------
// Fused GRU v5: grid (2 col-halves, NTOT/128), 512-thread blocks (8 waves).
// Block covers 128 rows x 64 cols; wave = 32 rows x 32 cols (acc 64 VGPR).
// Two-phase weight staging (WCI then WH) into one 52 KB buffer.
// Slot perm within col-half ch: slot ch*32+ni*16+j <-> col c0+ch*32+2*j+ni.
// A-frags from global (L2/L3-hot); no barriers inside the K-loop.
// ---------------------------------------------------------------------------
__global__ __launch_bounds__(512, 4) void k_gru5(
    const ushort* __restrict__ P, const ushort* __restrict__ Xin, ushort* __restrict__ Xout,
    const ushort* __restrict__ WCI, const ushort* __restrict__ WH,
    const float* __restrict__ bi, const float* __restrict__ bh)
{
    constexpr int LK = 136;
    __shared__ ushort Ws[3 * 64 * LK];     // 52224 B
    const int tid = threadIdx.x;
    const int c0 = blockIdx.x * 64;
    const size_t brow0 = (size_t)blockIdx.y * 128;
    const int w = tid >> 6, lane = tid & 63, quad = lane >> 4, l15 = lane & 15;
    const int ch = w & 1;                  // col-half within block
    const size_t row0 = brow0 + (w >> 1) * 32;
    const int cb = c0 + ch * 32;           // wave's 32-col base

    floatx4 accR[2][2], accZ[2][2], accI[2][2], accHN[2][2];
    #pragma unroll
    for (int i = 0; i < 2; ++i)
        #pragma unroll
        for (int j = 0; j < 2; ++j) {
            accR[i][j] = (floatx4)0.f; accZ[i][j] = (floatx4)0.f;
            accI[i][j] = (floatx4)0.f; accHN[i][j] = (floatx4)0.f;
        }

    #pragma unroll
    for (int h = 0; h < 2; ++h) {
        if (h) __syncthreads();                       // phase-0 readers done
        const ushort* Wsrc = h ? WH : WCI;
        for (int id = tid; id < 3072; id += 512) {    // 3*64*16 uint4
            int kc = id & 15, slot = (id >> 4) & 63, s = id >> 10;
            int w32 = slot & 31;
            int gcol = c0 + (slot >> 5) * 32 + 2 * (w32 & 15) + (w32 >> 4);
            *(uint4*)&Ws[(s * 64 + slot) * LK + kc * 8] =
                *(const uint4*)(Wsrc + (size_t)(s * 128 + gcol) * 128 + kc * 8);
        }
        __syncthreads();
        const ushort* Ah = h ? Xin : P;
        #pragma unroll
        for (int k4 = 0; k4 < 4; ++k4) {
            const int k0 = k4 * 32;
            short8 a[2];
            #pragma unroll
            for (int mi = 0; mi < 2; ++mi)
                a[mi] = glb_load8(Ah + (row0 + mi * 16 + l15) * H + k0 + quad * 8);
            #pragma unroll
            for (int s = 0; s < 3; ++s) {
                short8 b[2];
                #pragma unroll
                for (int ni = 0; ni < 2; ++ni)
                    b[ni] = lds_load8(&Ws[(s * 64 + ch * 32 + ni * 16 + l15) * LK + k0 + quad * 8]);
                #pragma unroll
                for (int mi = 0; mi < 2; ++mi)
                    #pragma unroll
                    for (int ni = 0; ni < 2; ++ni) {
                        if (s == 0)      accR[mi][ni] = mfma16(a[mi], b[ni], accR[mi][ni]);
                        else if (s == 1) accZ[mi][ni] = mfma16(a[mi], b[ni], accZ[mi][ni]);
                        else if (h == 0) accI[mi][ni] = mfma16(a[mi], b[ni], accI[mi][ni]);
                        else             accHN[mi][ni] = mfma16(a[mi], b[ni], accHN[mi][ni]);
                    }
            }
        }
    }

    // epilogue: lane holds cols (cb+2*l15, cb+2*l15+1)
    const int ce = cb + 2 * l15;
    float bir[2], biz[2], bin_[2], bhr[2], bhz[2], bhn[2];
    #pragma unroll
    for (int ni = 0; ni < 2; ++ni) {
        bir[ni] = bi[ce + ni]; biz[ni] = bi[128 + ce + ni]; bin_[ni] = bi[256 + ce + ni];
        bhr[ni] = bh[ce + ni]; bhz[ni] = bh[128 + ce + ni]; bhn[ni] = bh[256 + ce + ni];
    }
    #pragma unroll
    for (int mi = 0; mi < 2; ++mi)
        #pragma unroll
        for (int reg = 0; reg < 4; ++reg) {
            size_t r = row0 + mi * 16 + quad * 4 + reg;
            uint xo = *(const uint*)(Xin + r * H + ce);
            float xold[2] = { bflo(xo), bfhi(xo) };
            float res[2];
            #pragma unroll
            for (int ni = 0; ni < 2; ++ni) {
                float rs = accR[mi][ni][reg] + bir[ni] + bhr[ni];
                float zs = accZ[mi][ni][reg] + biz[ni] + bhz[ni];
                float rr = fsig(rs);
                float zz = fsig(zs);
                float nn = ftanh(accI[mi][ni][reg] + bin_[ni] + rr * (accHN[mi][ni][reg] + bhn[ni]));
                res[ni] = (1.f - zz) * nn + zz * xold[ni];
            }
            *(uint*)(Xout + r * H + ce) = packbf(res[0], res[1]);
        }
}

// ---------------------------------------------------------------------------
// Fused edge-MLP (unchanged from R5): 128 factor rows/block, T rewritten
// between stages, weights streamed per-64-col group.
// ---------------------------------------------------------------------------
__global__ __launch_bounds__(256, 3) void k_mlp(
    const ushort* __restrict__ Xf, const ushort* __restrict__ W1, const ushort* __restrict__ W2,
    const ushort* __restrict__ W3, const float* __restrict__ b1, const float* __restrict__ b2,
    const float* __restrict__ b3, ushort* __restrict__ msgs)
{
    constexpr int LK = 132;
    __shared__ ushort T[128 * LK];
    __shared__ ushort Wv[64 * LK];
    const int tid = threadIdx.x;
    const size_t row0 = (size_t)blockIdx.x * 128;
    const int w = tid >> 6, lane = tid & 63, quad = lane >> 4, l15 = lane & 15;
    const int wr = w * 32;

    for (int id = tid; id < 2048; id += 256) {
        int m = id >> 4, kc = (id & 15) * 8;
        *(uint4*)&T[m * LK + kc] = *(const uint4*)(Xf + (row0 + m) * H + kc);
    }

    #pragma unroll
    for (int stage = 0; stage < 3; ++stage) {
        const ushort* Wsrc = (stage == 0) ? W1 : (stage == 1) ? W2 : W3;
        const float* bias = (stage == 0) ? b1 : (stage == 1) ? b2 : b3;
        const int NCG = (stage == 2) ? 1 : 2;
        floatx4 acc[2][2][4];
        #pragma unroll
        for (int c = 0; c < 2; ++c)
            #pragma unroll
            for (int i = 0; i < 2; ++i)
                #pragma unroll
                for (int j = 0; j < 4; ++j) acc[c][i][j] = (floatx4)0.f;

        for (int cg = 0; cg < NCG; ++cg) {
            __syncthreads();
            for (int id = tid; id < 1024; id += 256) {
                int slot = id >> 4, kc = (id & 15) * 8;
                int gcol = cg * 64 + 4 * (slot & 15) + (slot >> 4);
                *(uint4*)&Wv[slot * LK + kc] = *(const uint4*)(Wsrc + (size_t)gcol * 128 + kc);
            }
            __syncthreads();
            for (int k0 = 0; k0 < 128; k0 += 32) {
                short8 a[2], b[4];
                #pragma unroll
                for (int mi = 0; mi < 2; ++mi)
                    a[mi] = lds_load8(&T[(wr + mi * 16 + l15) * LK + k0 + quad * 8]);
                #pragma unroll
                for (int ni = 0; ni < 4; ++ni)
                    b[ni] = lds_load8(&Wv[(ni * 16 + l15) * LK + k0 + quad * 8]);
                #pragma unroll
                for (int mi = 0; mi < 2; ++mi)
                    #pragma unroll
                    for (int ni = 0; ni < 4; ++ni)
                        acc[cg][mi][ni] = mfma16(a[mi], b[ni], acc[cg][mi][ni]);
            }
        }
        __syncthreads();

        if (stage < 2) {
            #pragma unroll
            for (int cg = 0; cg < 2; ++cg) {
                float bv[4];
                #pragma unroll
                for (int ni = 0; ni < 4; ++ni) bv[ni] = bias[cg * 64 + 4 * l15 + ni];
                #pragma unroll
                for (int mi = 0; mi < 2; ++mi)
                    #pragma unroll
                    for (int reg = 0; reg < 4; ++reg) {
                        int r = wr + mi * 16 + quad * 4 + reg;
                        float v[4];
                        #pragma unroll
                        for (int ni = 0; ni < 4; ++ni)
                            v[ni] = fmaxf(acc[cg][mi][ni][reg] + bv[ni], 0.f);
                        uint2 o = make_uint2(packbf(v[0], v[1]), packbf(v[2], v[3]));
                        *(uint2*)&T[r * LK + cg * 64 + 4 * l15] = o;
                    }
            }
            __syncthreads();
        } else {
            float bv[4];
            #pragma unroll
            for (int ni = 0; ni < 4; ++ni) bv[ni] = bias[4 * l15 + ni];
            #pragma unroll
            for (int mi = 0; mi < 2; ++mi)
                #pragma unroll
                for (int reg = 0; reg < 4; ++reg) {
                    size_t r = row0 + wr + mi * 16 + quad * 4 + reg;
                    float v[4];
                    #pragma unroll
                    for (int ni = 0; ni < 4; ++ni) v[ni] = acc[0][mi][ni][reg] + bv[ni];
                    uint2 o = make_uint2(packbf(v[0], v[1]), packbf(v[2], v[3]));
                    *(uint2*)(msgs + r * 64 + 4 * l15) = o;
                }
        }
    }
}

// ---------------------------------------------------------------------------
// Launch.  Workspace layout identical to R5 (115,605,504 B).
// ---------------------------------------------------------------------------
extern "C" void kernel_launch(void* const* d_in, const int* in_sizes, int n_in,
                              void* d_out, int out_size, void* d_ws, size_t ws_size,
                              hipStream_t stream) {
    (void)in_sizes; (void)n_in; (void)out_size;
    const float* jvals  = (const float*)d_in[0];
    const int*   row    = (const int*)d_in[2];
    const int*   col    = (const int*)d_in[3];
    const float* conv_W = (const float*)d_in[4];
    const float* gru_wi = (const float*)d_in[5];
    const float* gru_wh = (const float*)d_in[6];
    const float* gru_bi = (const float*)d_in[7];
    const float* gru_bh = (const float*)d_in[8];
    const float* mp_W1  = (const float*)d_in[9];
    const float* mp_b1  = (const float*)d_in[10];
    const float* mp_W2  = (const float*)d_in[11];
    const float* mp_b2  = (const float*)d_in[12];
    const float* mp_W3  = (const float*)d_in[13];
    const float* mp_b3  = (const float*)d_in[14];
    const float* ro_b1  = (const float*)d_in[16];
    const float* ro_b2  = (const float*)d_in[18];
    const float* ro_W3  = (const float*)d_in[19];
    const float* ro_b3  = (const float*)d_in[20];

    constexpr size_t OFF_XB  = 35651584ull;
    constexpr size_t OFF_P   = 71303168ull;
    constexpr size_t OFF_W   = 106954752ull;
    constexpr size_t OFF_WCI = 107347968ull;
    constexpr size_t OFF_NM  = 107544576ull;
    constexpr size_t OFF_HR1 = 109641728ull;
    constexpr size_t OFF_HR2 = 111738880ull;
    constexpr size_t OFF_CSR = 113836032ull;
    constexpr size_t OFF_L1  = 114032640ull;
    constexpr size_t OFF_L2  = 115081216ull;
    constexpr size_t WS_NEED = 115605504ull;
    if (ws_size < WS_NEED) return;

    char* ws = (char*)d_ws;
    ushort* Xa   = (ushort*)ws;
    ushort* Xb2  = (ushort*)(ws + OFF_XB);
    ushort* P    = (ushort*)(ws + OFF_P);
    ushort* msgs = (ushort*)(ws + OFF_P);     // after GRU layers (P dead)
    ushort* Wb   = (ushort*)(ws + OFF_W);
    ushort* Wci  = (ushort*)(ws + OFF_WCI);
    float*  nm   = (float*)(ws + OFF_NM);
    ushort* hr1  = (ushort*)(ws + OFF_HR1);
    ushort* hr2  = (ushort*)(ws + OFF_HR2);
    int* deg    = (int*)(ws + OFF_CSR);
    int* start  = deg + 8192;
    int* cur    = deg + 16384;
    int* deg2   = deg + 24576;
    int* start2 = deg + 32768;
    int* cur2   = deg + 40960;
    int* list   = (int*)(ws + OFF_L1);
    int* list2  = (int*)(ws + OFF_L2);

    dim3 blk(256);

    k_setup<<<70784, blk, 0, stream>>>(conv_W, gru_wi, gru_wh, mp_W1, mp_W2, mp_W3,
                                       (const float*)d_in[15], (const float*)d_in[17],
                                       jvals, Wb, Wci, Xa);
    k_zero_deg<<<32, blk, 0, stream>>>(deg, deg2);
    k_deg_count<<<N_EDGES / 256, blk, 0, stream>>>(row, col, deg, deg2);
    k_scan<<<1, blk, 0, stream>>>(deg, start, cur, deg2, start2, cur2);
    k_fill<<<N_EDGES / 256, blk, 0, stream>>>(row, col, cur, cur2, list, list2);

    ushort* Xcur = Xa;
    ushort* Xnxt = Xb2;
    for (int l = 0; l < 2; ++l) {
        k_agg<<<34816, blk, 0, stream>>>((uint*)P, (const uint*)Xcur, row, col, start, deg, list);
        k_gru5<<<dim3(2, NTOT / 128), dim3(512), 0, stream>>>(P, Xcur, Xnxt,
            Wci + (size_t)l * 49152, Wb + 81920, gru_bi, gru_bh);
        ushort* t = Xcur; Xcur = Xnxt; Xnxt = t;
    }
    // Xcur == Xa after 2 layers

    // fused edge MLP -> msgs (bf16)
    k_mlp<<<N_EDGES / 128, blk, 0, stream>>>(
        Xcur + (size_t)N_NODES * H, Wb + 131072, Wb + 147456, Wb + 163840,
        mp_b1, mp_b2, mp_b3, msgs);

    // node_msgs = segment_sum(msgs, row)
    k_nm_gather<<<N_NODES / 4, blk, 0, stream>>>(nm, msgs, start2, deg2, list2);

    // readout
    k_gemm2<128, true, true, false><<<N_NODES / 128, blk, 0, stream>>>(
        nm, Wb + 172032, ro_b1, hr1, 64, 64);
    k_gemm2<128, false, true, false><<<N_NODES / 128, blk, 0, stream>>>(
        hr1, Wb + 180224, ro_b2, hr2, 128, 128);
    k_logits<<<N_NODES / 4, blk, 0, stream>>>(hr2, ro_W3, ro_b3, (float*)d_out);
}